// Round 8
// baseline (308.020 us; speedup 1.0000x reference)
//
#include <hip/hip_runtime.h>

typedef __bf16 bf16;
typedef __bf16 bf16x2 __attribute__((ext_vector_type(2)));
typedef __bf16 bf16x4 __attribute__((ext_vector_type(4)));
typedef __bf16 bf16x8 __attribute__((ext_vector_type(8)));
typedef float f32x4 __attribute__((ext_vector_type(4)));

#define AS1 __attribute__((address_space(1)))
#define AS3 __attribute__((address_space(3)))

__device__ __forceinline__ void async_copy16(const void* g, void* l) {
  // global -> LDS direct, 16B/lane; LDS dest = wave-uniform base + lane*16.
  __builtin_amdgcn_global_load_lds((const AS1 void*)g, (AS3 void*)l, 16, 0, 0);
}

#define BB 8
#define CC 1024
#define QQ 128
#define EE 512
#define HH 1024
#define FOURE 2048

// ---------------------------------------------------------------------------
// prep:
//  bx [0,2048):    W1 (2048x1024) -> W1T
//  bx [2048,4096): W2 (1024x2048) -> W2T
//  bx [4096,4608): question per-batch transpose -> qT
//  bx [4608,5120): qm = question*wmul -> bf16 hi/lo (qmh/qml) + qw row-dots
//  bx == 5120:     zero q2c + zero panel flags
// ---------------------------------------------------------------------------
__global__ __launch_bounds__(256) void prep_kernel(
    const float* __restrict__ W1, const float* __restrict__ W2,
    const float* __restrict__ qst, const float* __restrict__ wmul,
    const float* __restrict__ wqv, bf16* __restrict__ W1T,
    bf16* __restrict__ W2T, bf16* __restrict__ qT,
    bf16* __restrict__ qmh, bf16* __restrict__ qml, float* __restrict__ qw,
    float* __restrict__ q2c, unsigned* __restrict__ flags) {
  __shared__ float tile[32][33];
  __shared__ float r4[4];
  int bx = blockIdx.x;
  int t = threadIdx.x;
  if (bx >= 5120) {
    for (int i = t; i < BB * EE; i += 256) q2c[i] = 0.f;
    if (t < 32) flags[t] = 0u;
    return;
  }
  if (bx >= 4608) {
    int i = bx - 4608;
    int half = t >> 7, tr = t & 127;
    int rowg = i * 2 + half;  // 0..1023 over (b,q)
    const float* qrow = qst + (size_t)rowg * EE;
    float4 qv = *(const float4*)&qrow[tr * 4];
    float4 wm4 = *(const float4*)&wmul[tr * 4];
    float4 wq4 = *(const float4*)&wqv[tr * 4];
    float m[4] = {qv.x * wm4.x, qv.y * wm4.y, qv.z * wm4.z, qv.w * wm4.w};
    bf16x4 h, l;
#pragma unroll
    for (int k = 0; k < 4; ++k) {
      bf16 hh = (bf16)m[k];
      h[k] = hh; l[k] = (bf16)(m[k] - (float)hh);
    }
    *(bf16x4*)&qmh[(size_t)rowg * EE + tr * 4] = h;
    *(bf16x4*)&qml[(size_t)rowg * EE + tr * 4] = l;
    float s = qv.x * wq4.x + qv.y * wq4.y + qv.z * wq4.z + qv.w * wq4.w;
#pragma unroll
    for (int off = 32; off; off >>= 1) s += __shfl_xor(s, off);
    if ((t & 63) == 0) r4[t >> 6] = s;
    __syncthreads();
    if (tr == 0) qw[rowg] = r4[half * 2] + r4[half * 2 + 1];
    return;
  }
  const float* src;
  bf16* dst;
  int R, C, idx;
  if (bx < 2048) {
    src = W1; dst = W1T; R = 2048; C = 1024; idx = bx;
  } else if (bx < 4096) {
    src = W2; dst = W2T; R = 1024; C = 2048; idx = bx - 2048;
  } else {
    int i = bx - 4096;
    int b = i >> 6; idx = i & 63;
    src = qst + (size_t)b * QQ * EE; dst = qT + (size_t)b * EE * QQ;
    R = 128; C = 512;
  }
  int ctiles = C >> 5;
  int by = idx / ctiles, cx = idx % ctiles;
  int tx = t & 31, ty = t >> 5;
#pragma unroll
  for (int rr = 0; rr < 4; ++rr)
    tile[ty + rr * 8][tx] = src[(size_t)(by * 32 + ty + rr * 8) * C + cx * 32 + tx];
  __syncthreads();
#pragma unroll
  for (int rr = 0; rr < 4; ++rr)
    dst[(size_t)(cx * 32 + ty + rr * 8) * R + by * 32 + tx] = (bf16)tile[tx][ty + rr * 8];
}

// ---------------------------------------------------------------------------
// fused_att: per (b = bid&7 [XCD-pin], 16 ctx rows). Unchanged from R7.
// ---------------------------------------------------------------------------
__global__ __launch_bounds__(256) void fused_att_kernel(
    const float* __restrict__ ctx, const bf16* __restrict__ qmh,
    const bf16* __restrict__ qml, const bf16* __restrict__ qT,
    const float* __restrict__ wc, const float* __restrict__ qw,
    float* __restrict__ smax, bf16* __restrict__ att) {
  __shared__ __align__(16) char U[32768];
  __shared__ float wc_s[EE];
  __shared__ float qw_s[QQ];
  __shared__ float cw_s[16];
  __shared__ bf16 P_lds[16][136];
  int bid = blockIdx.x;
  int t = threadIdx.x;
  int b = bid & 7;             // XCD pin
  int m0 = (bid >> 3) * 16;
  bf16* Bh = (bf16*)(U);                       // 2 bufs x 128x32 (8192B each)
  bf16* Bl = (bf16*)(U + 16384);               // 2 bufs
  float(*sim_s)[132] = (float(*)[132])(U);     // overlays B bufs (post-loop)
  bf16* c2q_lds = (bf16*)(U);                  // overlays (stage 2)
  for (int i = t; i < EE; i += 256) wc_s[i] = wc[i];
  if (t < QQ) qw_s[t] = qw[b * QQ + t];
  int wv = t >> 6, ln = t & 63;
  int rl = ln & 15, kq = ln >> 4;
  const float* Ag = ctx + ((size_t)b * CC + m0) * EE;
  const bf16* Bhg = qmh + (size_t)b * QQ * EE;
  const bf16* Blg = qml + (size_t)b * QQ * EE;
#pragma unroll
  for (int r = 0; r < 2; ++r) {
    int fb = (r * 4 + wv) * 1024 + ln * 16;
    int row = fb >> 6;
    int cq = ((fb >> 4) & 3) ^ ((row >> 1) & 3);
    async_copy16(Bhg + (size_t)row * EE + cq * 8, (char*)Bh + fb);
    async_copy16(Blg + (size_t)row * EE + cq * 8, (char*)Bl + fb);
  }
  const float* apb = Ag + (size_t)rl * EE + kq * 8;
  float4 a0 = *(const float4*)apb;
  float4 a1 = *(const float4*)(apb + 4);
  __syncthreads();
  f32x4 acc[2] = {};
  float cwp = 0.f;
  for (int it = 0; it < 16; ++it) {
    int k0 = it * 32;
    int cur = (it & 1) * 8192;
    int nxt = 8192 - cur;
    if (it + 1 < 16) {
#pragma unroll
      for (int r = 0; r < 2; ++r) {
        int fb = (r * 4 + wv) * 1024 + ln * 16;
        int row = fb >> 6;
        int cq = ((fb >> 4) & 3) ^ ((row >> 1) & 3);
        async_copy16(Bhg + (size_t)row * EE + k0 + 32 + cq * 8,
                     (char*)Bh + nxt + fb);
        async_copy16(Blg + (size_t)row * EE + k0 + 32 + cq * 8,
                     (char*)Bl + nxt + fb);
      }
    }
    float4 na0, na1;
    if (it + 1 < 16) {
      const float* ap2 = Ag + (size_t)rl * EE + k0 + 32 + kq * 8;
      na0 = *(const float4*)ap2;
      na1 = *(const float4*)(ap2 + 4);
    }
    float av[8] = {a0.x, a0.y, a0.z, a0.w, a1.x, a1.y, a1.z, a1.w};
    bf16x8 ah, al;
#pragma unroll
    for (int k = 0; k < 8; ++k) {
      bf16 hh = (bf16)av[k];
      ah[k] = hh; al[k] = (bf16)(av[k] - (float)hh);
    }
    if (wv == 0) {
#pragma unroll
      for (int k = 0; k < 8; ++k) cwp += av[k] * wc_s[k0 + kq * 8 + k];
    }
    bf16x8 bh[2], bl[2];
#pragma unroll
    for (int j = 0; j < 2; ++j) {
      int r = wv * 32 + j * 16 + rl;
      int sl = (kq ^ ((r >> 1) & 3)) * 8;
      bh[j] = *(const bf16x8*)((const char*)Bh + cur + (r * 32 + sl) * 2);
      bl[j] = *(const bf16x8*)((const char*)Bl + cur + (r * 32 + sl) * 2);
    }
#pragma unroll
    for (int j = 0; j < 2; ++j) {
      acc[j] = __builtin_amdgcn_mfma_f32_16x16x32_bf16(ah, bh[j], acc[j], 0, 0, 0);
      acc[j] = __builtin_amdgcn_mfma_f32_16x16x32_bf16(ah, bl[j], acc[j], 0, 0, 0);
      acc[j] = __builtin_amdgcn_mfma_f32_16x16x32_bf16(al, bh[j], acc[j], 0, 0, 0);
    }
    a0 = na0; a1 = na1;
    __syncthreads();
  }
  if (wv == 0) {
    float s = cwp;
    s += __shfl_xor(s, 16);
    s += __shfl_xor(s, 32);
    if (ln < 16) cw_s[ln] = s;
  }
#pragma unroll
  for (int j = 0; j < 2; ++j) {
    int col = wv * 32 + j * 16 + rl;
    float qv = qw_s[col];
    int rbase = kq * 4;
#pragma unroll
    for (int r = 0; r < 4; ++r) sim_s[rbase + r][col] = acc[j][r] + qv;
  }
  __syncthreads();
  {
    int row = t >> 4, cb = t & 15;
    float v[8];
    float mx = -3.4e38f;
#pragma unroll
    for (int k = 0; k < 8; ++k) {
      v[k] = sim_s[row][cb + 16 * k];
      mx = fmaxf(mx, v[k]);
    }
    mx = fmaxf(mx, __shfl_xor(mx, 1));
    mx = fmaxf(mx, __shfl_xor(mx, 2));
    mx = fmaxf(mx, __shfl_xor(mx, 4));
    mx = fmaxf(mx, __shfl_xor(mx, 8));
    float sm = 0.f;
#pragma unroll
    for (int k = 0; k < 8; ++k) { v[k] = __expf(v[k] - mx); sm += v[k]; }
    sm += __shfl_xor(sm, 1);
    sm += __shfl_xor(sm, 2);
    sm += __shfl_xor(sm, 4);
    sm += __shfl_xor(sm, 8);
    float inv = 1.0f / sm;
#pragma unroll
    for (int k = 0; k < 8; ++k) P_lds[row][cb + 16 * k] = (bf16)(v[k] * inv);
    if (cb == 0) smax[b * CC + m0 + row] = mx + cw_s[row];
  }
  __syncthreads();
  f32x4 acc2[8] = {};
  const bf16* qTb = qT + (size_t)b * EE * QQ;
#pragma unroll
  for (int kk = 0; kk < 4; ++kk) {
    bf16x8 af2;
    {
      bf16x4 lo = *(const bf16x4*)&P_lds[rl][kk * 32 + kq * 8];
      bf16x4 hi = *(const bf16x4*)&P_lds[rl][kk * 32 + kq * 8 + 4];
      af2[0] = lo[0]; af2[1] = lo[1]; af2[2] = lo[2]; af2[3] = lo[3];
      af2[4] = hi[0]; af2[5] = hi[1]; af2[6] = hi[2]; af2[7] = hi[3];
    }
#pragma unroll
    for (int j = 0; j < 8; ++j) {
      int n = wv * 128 + j * 16 + rl;
      bf16x8 bfr = *(const bf16x8*)&qTb[(size_t)n * QQ + kk * 32 + kq * 8];
      acc2[j] = __builtin_amdgcn_mfma_f32_16x16x32_bf16(af2, bfr, acc2[j], 0, 0, 0);
    }
  }
#pragma unroll
  for (int j = 0; j < 8; ++j) {
    int col = wv * 128 + j * 16 + rl;
    int rbase = kq * 4;
#pragma unroll
    for (int r = 0; r < 4; ++r)
      c2q_lds[(size_t)(rbase + r) * 520 + col] = (bf16)acc2[j][r];
  }
  __syncthreads();
  {
    int row = t >> 4, tc = t & 15;
    const float* crow = ctx + ((size_t)(b * CC + m0 + row)) * EE;
    bf16* arow_p = att + ((size_t)(b * CC + m0 + row)) * FOURE;
#pragma unroll
    for (int cc = 0; cc < 4; ++cc) {
      int col = cc * 128 + tc * 8;
      bf16x8 q8 = *(const bf16x8*)&c2q_lds[(size_t)row * 520 + col];
      float4 v0 = *(const float4*)&crow[col];
      float4 v1 = *(const float4*)&crow[col + 4];
      float cv[8] = {v0.x, v0.y, v0.z, v0.w, v1.x, v1.y, v1.z, v1.w};
      bf16x8 o0, o2;
#pragma unroll
      for (int k = 0; k < 8; ++k) {
        o0[k] = (bf16)cv[k];
        o2[k] = (bf16)(cv[k] * (float)q8[k]);
      }
      *(bf16x8*)&arow_p[col] = o0;
      *(bf16x8*)&arow_p[EE + col] = q8;
      *(bf16x8*)&arow_p[2 * EE + col] = o2;
    }
  }
}

// ---------------------------------------------------------------------------
// q2c: fused softmax over c. Grid 256 (1-D), batch->XCD pinned. Unchanged.
// ---------------------------------------------------------------------------
__global__ __launch_bounds__(256) void q2c_kernel(
    const float* __restrict__ ctx, const float* __restrict__ smax,
    float* __restrict__ q2c) {
  int b = blockIdx.x & 7, ch = blockIdx.x >> 3;
  int t = threadIdx.x;
  __shared__ float red4m[4], red4s[4];
  __shared__ float w_s[32];
  float v[4];
  float mx = -3.4e38f;
#pragma unroll
  for (int i = 0; i < 4; ++i) {
    v[i] = smax[b * CC + i * 256 + t];
    mx = fmaxf(mx, v[i]);
  }
#pragma unroll
  for (int off = 32; off; off >>= 1) mx = fmaxf(mx, __shfl_xor(mx, off));
  if ((t & 63) == 0) red4m[t >> 6] = mx;
  __syncthreads();
  mx = fmaxf(fmaxf(red4m[0], red4m[1]), fmaxf(red4m[2], red4m[3]));
  float sm = 0.f;
#pragma unroll
  for (int i = 0; i < 4; ++i) sm += __expf(v[i] - mx);
#pragma unroll
  for (int off = 32; off; off >>= 1) sm += __shfl_xor(sm, off);
  if ((t & 63) == 0) red4s[t >> 6] = sm;
  __syncthreads();
  float inv = 1.0f / (red4s[0] + red4s[1] + red4s[2] + red4s[3]);
  if (t < 32) w_s[t] = __expf(smax[b * CC + ch * 32 + t] - mx) * inv;
  __syncthreads();
  int e = t * 2;
  const float* cb = ctx + ((size_t)b * CC + ch * 32) * EE;
  float a0 = 0.f, a1 = 0.f;
#pragma unroll 8
  for (int r = 0; r < 32; ++r) {
    float2 vv = *(const float2*)&cb[(size_t)r * EE + e];
    float w = w_s[r];
    a0 += w * vv.x;
    a1 += w * vv.y;
  }
  atomicAdd(&q2c[b * EE + e], a0);
  atomicAdd(&q2c[b * EE + e + 1], a1);
}

// ---------------------------------------------------------------------------
// att part 3: att[:, 3E:4E] = ctx * q2c[b]. Batch->XCD pinned. Unchanged.
// ---------------------------------------------------------------------------
__global__ __launch_bounds__(256) void att3_kernel(
    const float* __restrict__ ctx, const float* __restrict__ q2c,
    bf16* __restrict__ att) {
  int b = blockIdx.x & 7;
  int inner = (blockIdx.x >> 3) * 256 + threadIdx.x;
  int row = b * CC + (inner >> 6);
  int e = (inner & 63) * 8;
  float4 v0 = *(const float4*)&ctx[(size_t)row * EE + e];
  float4 v1 = *(const float4*)&ctx[(size_t)row * EE + e + 4];
  float4 g0 = *(const float4*)&q2c[b * EE + e];
  float4 g1 = *(const float4*)&q2c[b * EE + e + 4];
  bf16x8 o;
  o[0] = (bf16)(v0.x * g0.x); o[1] = (bf16)(v0.y * g0.y);
  o[2] = (bf16)(v0.z * g0.z); o[3] = (bf16)(v0.w * g0.w);
  o[4] = (bf16)(v1.x * g1.x); o[5] = (bf16)(v1.y * g1.y);
  o[6] = (bf16)(v1.z * g1.z); o[7] = (bf16)(v1.w * g1.w);
  *(bf16x8*)&att[(size_t)row * FOURE + 3 * EE + e] = o;
}

// ---------------------------------------------------------------------------
// FUSED MLP: GEMM1 (256x128 tile, 2-phase ring-3) -> per-panel flag sync ->
// GEMM2 (256x256 tile, 8-phase). Grid 256 = 1 block/CU (LDS 144KB forces it;
// grid == CU count -> all blocks co-resident -> per-panel spin is
// deadlock-free). Block bid: panel mt = bid>>3 for BOTH phases; GEMM2 waits
// only on its own panel's 8 producers (device-scope acquire/release per G16)
// instead of the old full-grid kernel boundary -> GEMM1 stragglers overlap
// GEMM2 of finished panels. K-loop bodies verbatim from the frozen kernels.
// ---------------------------------------------------------------------------
__global__ __launch_bounds__(512, 2) void gemm_fused_kernel(
    const bf16* __restrict__ attA, const bf16* __restrict__ W1T,
    const float* __restrict__ b1, bf16* __restrict__ hbuf,
    const bf16* __restrict__ W2T, const float* __restrict__ b2,
    const float* __restrict__ mask, float* __restrict__ out,
    unsigned* __restrict__ flags) {
  __shared__ __align__(16) char LDSU[147456];
  int bid = blockIdx.x;
  int t = threadIdx.x, wv = t >> 6, ln = t & 63;
  int rl = ln & 15, kq = ln >> 4;
  int mt = bid >> 3;           // row panel 0..31 (both phases)
  int m0 = mt << 8;

  // ================= phase 1: GEMM1 tile, K=2048, N=1024 ==================
  {
    const int K = 2048, N = 1024;
    int n0 = (bid & 7) << 7;   // bid%8 -> XCD shares the same W1T B-panel
    int wm = wv >> 1, wn = wv & 1;
    int NT = K >> 6;
    auto As = [&](int buf) { return (bf16*)(LDSU + buf * 32768); };
    auto Bs = [&](int buf) { return (bf16*)(LDSU + 98304 + buf * 16384); };
    auto stageA = [&](int buf, int kt, int r) {
      int k0 = kt << 6;
      int fb = r * 8192 + t * 16;
      int row = fb >> 7;
      int q = ((fb >> 4) & 7) ^ (row & 7);
      async_copy16(attA + (size_t)(m0 + row) * K + k0 + q * 8,
                   (char*)As(buf) + fb);
    };
    auto stageB = [&](int buf, int kt, int r) {
      int k0 = kt << 6;
      int fb = r * 8192 + t * 16;
      int row = fb >> 7;
      int q = ((fb >> 4) & 7) ^ (row & 7);
      async_copy16(W1T + (size_t)(n0 + row) * K + k0 + q * 8,
                   (char*)Bs(buf) + fb);
    };
#pragma unroll
    for (int r = 0; r < 4; ++r) stageA(0, 0, r);
#pragma unroll
    for (int r = 0; r < 2; ++r) stageB(0, 0, r);
#pragma unroll
    for (int r = 0; r < 4; ++r) stageA(1, 1, r);
#pragma unroll
    for (int r = 0; r < 2; ++r) stageB(1, 1, r);
    asm volatile("s_waitcnt vmcnt(6)" ::: "memory");
    __builtin_amdgcn_s_barrier();

    f32x4 acc[4][4] = {};
    int cur = 0;
    for (int kt = 0; kt < NT; ++kt) {
      const bf16* Ab = As(cur);
      const bf16* Bb = Bs(cur);
      int nxt = cur + 2; if (nxt >= 3) nxt -= 3;
      bool pf = (kt + 2) < NT;
      bf16x8 af0[2][2], bfr[2][4];
#pragma unroll
      for (int ks = 0; ks < 2; ++ks) {
        int c = ks * 4 + kq;
#pragma unroll
        for (int i = 0; i < 2; ++i) {
          int row = wm * 64 + i * 16 + rl;
          af0[ks][i] = *(const bf16x8*)&Ab[row * 64 + ((c ^ (row & 7)) * 8)];
        }
#pragma unroll
        for (int j = 0; j < 4; ++j) {
          int row = wn * 64 + j * 16 + rl;
          bfr[ks][j] = *(const bf16x8*)&Bb[row * 64 + ((c ^ (row & 7)) * 8)];
        }
      }
      if (pf) { stageA(nxt, kt + 2, 0); stageA(nxt, kt + 2, 1); stageA(nxt, kt + 2, 2); }
      __builtin_amdgcn_s_barrier();
      asm volatile("s_waitcnt lgkmcnt(0)" ::: "memory");
      __builtin_amdgcn_sched_barrier(0);
      __builtin_amdgcn_s_setprio(1);
#pragma unroll
      for (int ks = 0; ks < 2; ++ks)
#pragma unroll
        for (int i = 0; i < 2; ++i)
#pragma unroll
          for (int j = 0; j < 4; ++j)
            acc[i][j] = __builtin_amdgcn_mfma_f32_16x16x32_bf16(
                af0[ks][i], bfr[ks][j], acc[i][j], 0, 0, 0);
      __builtin_amdgcn_s_setprio(0);
      __builtin_amdgcn_s_barrier();
      bf16x8 af1[2][2];
#pragma unroll
      for (int ks = 0; ks < 2; ++ks) {
        int c = ks * 4 + kq;
#pragma unroll
        for (int i = 0; i < 2; ++i) {
          int row = wm * 64 + (i + 2) * 16 + rl;
          af1[ks][i] = *(const bf16x8*)&Ab[row * 64 + ((c ^ (row & 7)) * 8)];
        }
      }
      if (pf) { stageA(nxt, kt + 2, 3); stageB(nxt, kt + 2, 0); stageB(nxt, kt + 2, 1); }
      __builtin_amdgcn_s_barrier();
      asm volatile("s_waitcnt lgkmcnt(0)" ::: "memory");
      __builtin_amdgcn_sched_barrier(0);
      __builtin_amdgcn_s_setprio(1);
#pragma unroll
      for (int ks = 0; ks < 2; ++ks)
#pragma unroll
        for (int i = 0; i < 2; ++i)
#pragma unroll
          for (int j = 0; j < 4; ++j)
            acc[i + 2][j] = __builtin_amdgcn_mfma_f32_16x16x32_bf16(
                af1[ks][i], bfr[ks][j], acc[i + 2][j], 0, 0, 0);
      __builtin_amdgcn_s_setprio(0);
      if (kt + 1 < NT) {
        if (pf) asm volatile("s_waitcnt vmcnt(6)" ::: "memory");
        else    asm volatile("s_waitcnt vmcnt(0)" ::: "memory");
        __builtin_amdgcn_s_barrier();
      }
      cur += 1; if (cur >= 3) cur -= 3;
    }
    // epilogue -> hbuf bf16, mask, no relu; write-coalesced
    float bv4[4];
#pragma unroll
    for (int j = 0; j < 4; ++j) bv4[j] = b1[n0 + wn * 64 + j * 16 + rl];
#pragma unroll
    for (int i = 0; i < 4; ++i) {
      int rbase = m0 + wm * 64 + i * 16 + (kq << 2);
#pragma unroll
      for (int r = 0; r < 4; ++r) {
        int row = rbase + r;
        float mk = mask[row];
#pragma unroll
        for (int j = 0; j < 4; ++j) {
          int col = n0 + wn * 64 + j * 16 + rl;
          float v = acc[i][j][r] + bv4[j];
          v *= mk;
          hbuf[(size_t)row * N + col] = (bf16)v;
        }
      }
    }
  }

  // ---- publish panel tile; wait for the panel's 8 producers ----
  __threadfence();          // device-scope: hbuf stores visible before flag
  __syncthreads();
  if (t == 0) {
    __hip_atomic_fetch_add(&flags[mt], 1u, __ATOMIC_RELEASE,
                           __HIP_MEMORY_SCOPE_AGENT);
    while (__hip_atomic_load(&flags[mt], __ATOMIC_ACQUIRE,
                             __HIP_MEMORY_SCOPE_AGENT) < 8u)
      __builtin_amdgcn_s_sleep(2);
  }
  __syncthreads();

  // ================= phase 2: GEMM2 tile, K=1024, N=2048 ==================
  {
    const int K = 1024, N = 2048;
    int n0 = (bid & 7) << 8;   // bid%8 -> XCD shares the same W2T B-panel
    int wm = wv >> 2, wn = wv & 3;
    int NT = K >> 6;
    int chunk = t & 7;
    auto As2 = [&](int buf) { return (bf16*)(LDSU + buf * 32768); };
    auto Bs2 = [&](int buf) { return (bf16*)(LDSU + 65536 + buf * 32768); };
    auto stage = [&](int buf, int k1, int arr, int half, int r) {
      int fb = r * 8192 + t * 16;
      int phys = half * 128 + (fb >> 7);
      int q = chunk ^ (phys & 7);
      if (arr == 0) {
        int lg = ((phys >> 6) & 1) * 128 + (phys >> 7) * 64 + (phys & 63);
        async_copy16(hbuf + (size_t)(m0 + lg) * K + k1 + q * 8,
                     (char*)As2(buf) + half * 16384 + fb);
      } else {
        int lg = ((phys >> 5) & 3) * 64 + (phys >> 7) * 32 + (phys & 31);
        async_copy16(W2T + (size_t)(n0 + lg) * K + k1 + q * 8,
                     (char*)Bs2(buf) + half * 16384 + fb);
      }
    };
    auto ldA = [&](const bf16* Ab, int i, int ks) {
      int pr = (i >> 2) * 128 + wm * 64 + (i & 3) * 16 + rl;
      return *(const bf16x8*)&Ab[pr * 64 + (((ks * 4 + kq) ^ (pr & 7)) * 8)];
    };
    auto ldB = [&](const bf16* Bb, int j, int ks) {
      int pr = (j >> 1) * 128 + wn * 32 + (j & 1) * 16 + rl;
      return *(const bf16x8*)&Bb[pr * 64 + (((ks * 4 + kq) ^ (pr & 7)) * 8)];
    };

    stage(0, 0, 0, 0, 0); stage(0, 0, 0, 0, 1);
    stage(0, 0, 1, 0, 0); stage(0, 0, 1, 0, 1);
    stage(0, 0, 0, 1, 0); stage(0, 0, 0, 1, 1);
    stage(0, 0, 1, 1, 0); stage(0, 0, 1, 1, 1);
    stage(1, 64, 0, 0, 0); stage(1, 64, 0, 0, 1);
    stage(1, 64, 1, 0, 0); stage(1, 64, 1, 0, 1);
    asm volatile("s_waitcnt vmcnt(4)" ::: "memory");
    __builtin_amdgcn_s_barrier();

    f32x4 acc[8][4] = {};
    bf16x8 aX[4][2], bL[2][2], bH[2][2];
    int NI = NT >> 1;
    for (int it = 0; it < NI; ++it) {
      const bf16* A0 = As2(0);
      const bf16* B0 = Bs2(0);
      const bf16* A1 = As2(1);
      const bf16* B1 = Bs2(1);
      int t1k = ((it << 1) + 1) << 6;
      int t2k = ((it << 1) + 2) << 6;
      int t3k = ((it << 1) + 3) << 6;
      bool s2 = ((it << 1) + 2) < NT;
      bool s3 = ((it << 1) + 3) < NT;
      bool last = (it == NI - 1);

      // ---- p1 ----
#pragma unroll
      for (int i = 0; i < 4; ++i) { aX[i][0] = ldA(A0, i, 0); aX[i][1] = ldA(A0, i, 1); }
#pragma unroll
      for (int j = 0; j < 2; ++j) { bL[j][0] = ldB(B0, j, 0); bL[j][1] = ldB(B0, j, 1); }
      stage(1, t1k, 0, 1, 0); stage(1, t1k, 0, 1, 1);
      asm volatile("s_waitcnt lgkmcnt(8)" ::: "memory");
      __builtin_amdgcn_s_barrier();
      asm volatile("s_waitcnt lgkmcnt(0)" ::: "memory");
      __builtin_amdgcn_sched_barrier(0);
      __builtin_amdgcn_s_setprio(1);
#pragma unroll
      for (int ks = 0; ks < 2; ++ks)
#pragma unroll
        for (int i = 0; i < 4; ++i)
#pragma unroll
          for (int j = 0; j < 2; ++j)
            acc[i][j] = __builtin_amdgcn_mfma_f32_16x16x32_bf16(
                aX[i][ks], bL[j][ks], acc[i][j], 0, 0, 0);
      __builtin_amdgcn_s_setprio(0);
      __builtin_amdgcn_s_barrier();
      // ---- p2 ----
#pragma unroll
      for (int j = 0; j < 2; ++j) { bH[j][0] = ldB(B0, j + 2, 0); bH[j][1] = ldB(B0, j + 2, 1); }
      stage(1, t1k, 1, 1, 0); stage(1, t1k, 1, 1, 1);
      __builtin_amdgcn_s_barrier();
      asm volatile("s_waitcnt lgkmcnt(0)" ::: "memory");
      __builtin_amdgcn_sched_barrier(0);
      __builtin_amdgcn_s_setprio(1);
#pragma unroll
      for (int ks = 0; ks < 2; ++ks)
#pragma unroll
        for (int i = 0; i < 4; ++i)
#pragma unroll
          for (int j = 0; j < 2; ++j)
            acc[i][j + 2] = __builtin_amdgcn_mfma_f32_16x16x32_bf16(
                aX[i][ks], bH[j][ks], acc[i][j + 2], 0, 0, 0);
      __builtin_amdgcn_s_setprio(0);
      __builtin_amdgcn_s_barrier();
      // ---- p3 ----
#pragma unroll
      for (int i = 0; i < 4; ++i) { aX[i][0] = ldA(A0, i + 4, 0); aX[i][1] = ldA(A0, i + 4, 1); }
      if (s2) { stage(0, t2k, 0, 0, 0); stage(0, t2k, 0, 0, 1); }
      __builtin_amdgcn_s_barrier();
      asm volatile("s_waitcnt lgkmcnt(0)" ::: "memory");
      __builtin_amdgcn_sched_barrier(0);
      __builtin_amdgcn_s_setprio(1);
#pragma unroll
      for (int ks = 0; ks < 2; ++ks)
#pragma unroll
        for (int i = 0; i < 4; ++i)
#pragma unroll
          for (int j = 0; j < 2; ++j)
            acc[i + 4][j] = __builtin_amdgcn_mfma_f32_16x16x32_bf16(
                aX[i][ks], bL[j][ks], acc[i + 4][j], 0, 0, 0);
      __builtin_amdgcn_s_setprio(0);
      __builtin_amdgcn_s_barrier();
      // ---- p4 ----
      if (s2) { stage(0, t2k, 1, 0, 0); stage(0, t2k, 1, 0, 1); }
      __builtin_amdgcn_s_barrier();
      __builtin_amdgcn_s_setprio(1);
#pragma unroll
      for (int ks = 0; ks < 2; ++ks)
#pragma unroll
        for (int i = 0; i < 4; ++i)
#pragma unroll
          for (int j = 0; j < 2; ++j)
            acc[i + 4][j + 2] = __builtin_amdgcn_mfma_f32_16x16x32_bf16(
                aX[i][ks], bH[j][ks], acc[i + 4][j + 2], 0, 0, 0);
      __builtin_amdgcn_s_setprio(0);
      if (last) asm volatile("s_waitcnt vmcnt(0)" ::: "memory");
      else      asm volatile("s_waitcnt vmcnt(4)" ::: "memory");
      __builtin_amdgcn_s_barrier();
      // ---- p5 ----
#pragma unroll
      for (int i = 0; i < 4; ++i) { aX[i][0] = ldA(A1, i, 0); aX[i][1] = ldA(A1, i, 1); }
#pragma unroll
      for (int j = 0; j < 2; ++j) { bL[j][0] = ldB(B1, j, 0); bL[j][1] = ldB(B1, j, 1); }
      if (s2) { stage(0, t2k, 0, 1, 0); stage(0, t2k, 0, 1, 1); }
      asm volatile("s_waitcnt lgkmcnt(8)" ::: "memory");
      __builtin_amdgcn_s_barrier();
      asm volatile("s_waitcnt lgkmcnt(0)" ::: "memory");
      __builtin_amdgcn_sched_barrier(0);
      __builtin_amdgcn_s_setprio(1);
#pragma unroll
      for (int ks = 0; ks < 2; ++ks)
#pragma unroll
        for (int i = 0; i < 4; ++i)
#pragma unroll
          for (int j = 0; j < 2; ++j)
            acc[i][j] = __builtin_amdgcn_mfma_f32_16x16x32_bf16(
                aX[i][ks], bL[j][ks], acc[i][j], 0, 0, 0);
      __builtin_amdgcn_s_setprio(0);
      __builtin_amdgcn_s_barrier();
      // ---- p6 ----
#pragma unroll
      for (int j = 0; j < 2; ++j) { bH[j][0] = ldB(B1, j + 2, 0); bH[j][1] = ldB(B1, j + 2, 1); }
      if (s2) { stage(0, t2k, 1, 1, 0); stage(0, t2k, 1, 1, 1); }
      __builtin_amdgcn_s_barrier();
      asm volatile("s_waitcnt lgkmcnt(0)" ::: "memory");
      __builtin_amdgcn_sched_barrier(0);
      __builtin_amdgcn_s_setprio(1);
#pragma unroll
      for (int ks = 0; ks < 2; ++ks)
#pragma unroll
        for (int i = 0; i < 4; ++i)
#pragma unroll
          for (int j = 0; j < 2; ++j)
            acc[i][j + 2] = __builtin_amdgcn_mfma_f32_16x16x32_bf16(
                aX[i][ks], bH[j][ks], acc[i][j + 2], 0, 0, 0);
      __builtin_amdgcn_s_setprio(0);
      __builtin_amdgcn_s_barrier();
      // ---- p7 ----
#pragma unroll
      for (int i = 0; i < 4; ++i) { aX[i][0] = ldA(A1, i + 4, 0); aX[i][1] = ldA(A1, i + 4, 1); }
      if (s3) { stage(1, t3k, 0, 0, 0); stage(1, t3k, 0, 0, 1); }
      __builtin_amdgcn_s_barrier();
      asm volatile("s_waitcnt lgkmcnt(0)" ::: "memory");
      __builtin_amdgcn_sched_barrier(0);
      __builtin_amdgcn_s_setprio(1);
#pragma unroll
      for (int ks = 0; ks < 2; ++ks)
#pragma unroll
        for (int i = 0; i < 4; ++i)
#pragma unroll
          for (int j = 0; j < 2; ++j)
            acc[i + 4][j] = __builtin_amdgcn_mfma_f32_16x16x32_bf16(
                aX[i][ks], bL[j][ks], acc[i + 4][j], 0, 0, 0);
      __builtin_amdgcn_s_setprio(0);
      __builtin_amdgcn_s_barrier();
      // ---- p8 ----
      if (s3) { stage(1, t3k, 1, 0, 0); stage(1, t3k, 1, 0, 1); }
      __builtin_amdgcn_s_barrier();
      __builtin_amdgcn_s_setprio(1);
#pragma unroll
      for (int ks = 0; ks < 2; ++ks)
#pragma unroll
        for (int i = 0; i < 4; ++i)
#pragma unroll
          for (int j = 0; j < 2; ++j)
            acc[i + 4][j + 2] = __builtin_amdgcn_mfma_f32_16x16x32_bf16(
                aX[i][ks], bH[j][ks], acc[i + 4][j + 2], 0, 0, 0);
      __builtin_amdgcn_s_setprio(0);
      if (!last) {
        asm volatile("s_waitcnt vmcnt(4)" ::: "memory");
        __builtin_amdgcn_s_barrier();
      }
    }

    // epilogue -> out f32, relu, mask; write-coalesced
    float bv4[4];
#pragma unroll
    for (int j = 0; j < 4; ++j) bv4[j] = b2[n0 + wn * 64 + j * 16 + rl];
#pragma unroll
    for (int i = 0; i < 8; ++i) {
      int rbase = m0 + wm * 128 + i * 16 + (kq << 2);
#pragma unroll
      for (int r = 0; r < 4; ++r) {
        int row = rbase + r;
        float mk = mask[row];
#pragma unroll
        for (int j = 0; j < 4; ++j) {
          int col = n0 + wn * 64 + j * 16 + rl;
          float v = acc[i][j][r] + bv4[j];
          v *= mk;
          v = fmaxf(v, 0.f);
          out[(size_t)row * N + col] = v;
        }
      }
    }
  }
}

// ---------------------------------------------------------------------------
// launcher — 5 kernels (GEMM1+GEMM2 fused; flags zeroed in prep)
// ---------------------------------------------------------------------------
extern "C" void kernel_launch(void* const* d_in, const int* in_sizes, int n_in,
                              void* d_out, int out_size, void* d_ws, size_t ws_size,
                              hipStream_t stream) {
  const float* ctx = (const float*)d_in[0];
  const float* qst = (const float*)d_in[1];
  const float* mask = (const float*)d_in[2];
  const float* wqv = (const float*)d_in[3];
  const float* wcv = (const float*)d_in[4];
  const float* wmul = (const float*)d_in[5];
  const float* W1 = (const float*)d_in[6];
  const float* b1 = (const float*)d_in[7];
  const float* W2 = (const float*)d_in[8];
  const float* b2 = (const float*)d_in[9];
  float* out = (float*)d_out;
  char* ws = (char*)d_ws;

  bf16* att = (bf16*)(ws);                  // 33554432
  bf16* hbuf = (bf16*)(ws + 33554432);      // 16777216
  bf16* W1T = (bf16*)(ws + 50331648);       // 4194304
  bf16* W2T = (bf16*)(ws + 54525952);       // 4194304
  bf16* qT = (bf16*)(ws + 58720256);        // 1048576
  bf16* qmh = (bf16*)(ws + 59768832);       // 1048576
  bf16* qml = (bf16*)(ws + 60817408);       // 1048576
  float* smax = (float*)(ws + 61865984);    // 32768
  float* q2c = (float*)(ws + 61898752);     // 16384
  float* qw = (float*)(ws + 61915136);      // 4096
  unsigned* flags = (unsigned*)(ws + 61919232);  // 128

  prep_kernel<<<5121, 256, 0, stream>>>(W1, W2, qst, wmul, wqv,
                                        W1T, W2T, qT, qmh, qml, qw, q2c, flags);
  fused_att_kernel<<<512, 256, 0, stream>>>(ctx, qmh, qml, qT, wcv,
                                            qw, smax, att);
  q2c_kernel<<<256, 256, 0, stream>>>(ctx, smax, q2c);
  att3_kernel<<<2048, 256, 0, stream>>>(ctx, q2c, att);
  // fused MLP: h = (att@W1+b1)*mask -> out = relu((h@W2+b2)*mask)
  gemm_fused_kernel<<<256, 512, 0, stream>>>(att, W1T, b1, hbuf,
                                             W2T, b2, mask, out, flags);
}

// Round 9
// 291.779 us; speedup vs baseline: 1.0557x; 1.0557x over previous
//
#include <hip/hip_runtime.h>

typedef __bf16 bf16;
typedef __bf16 bf16x2 __attribute__((ext_vector_type(2)));
typedef __bf16 bf16x4 __attribute__((ext_vector_type(4)));
typedef __bf16 bf16x8 __attribute__((ext_vector_type(8)));
typedef float f32x4 __attribute__((ext_vector_type(4)));

#define AS1 __attribute__((address_space(1)))
#define AS3 __attribute__((address_space(3)))

__device__ __forceinline__ void async_copy16(const void* g, void* l) {
  // global -> LDS direct, 16B/lane; LDS dest = wave-uniform base + lane*16.
  __builtin_amdgcn_global_load_lds((const AS1 void*)g, (AS3 void*)l, 16, 0, 0);
}

#define BB 8
#define CC 1024
#define QQ 128
#define EE 512
#define HH 1024
#define FOURE 2048

// ---------------------------------------------------------------------------
// prep:
//  bx [0,2048):    W1 (2048x1024) -> W1T
//  bx [2048,4096): W2 (1024x2048) -> W2T
//  bx [4096,4608): question per-batch transpose -> qT
//  bx [4608,5120): qm = question*wmul -> bf16 hi/lo (qmh/qml) + qw row-dots
//  bx == 5120:     zero q2c + zero panel flags
// ---------------------------------------------------------------------------
__global__ __launch_bounds__(256) void prep_kernel(
    const float* __restrict__ W1, const float* __restrict__ W2,
    const float* __restrict__ qst, const float* __restrict__ wmul,
    const float* __restrict__ wqv, bf16* __restrict__ W1T,
    bf16* __restrict__ W2T, bf16* __restrict__ qT,
    bf16* __restrict__ qmh, bf16* __restrict__ qml, float* __restrict__ qw,
    float* __restrict__ q2c, unsigned* __restrict__ flags) {
  __shared__ float tile[32][33];
  __shared__ float r4[4];
  int bx = blockIdx.x;
  int t = threadIdx.x;
  if (bx >= 5120) {
    for (int i = t; i < BB * EE; i += 256) q2c[i] = 0.f;
    if (t < 32) flags[t] = 0u;
    return;
  }
  if (bx >= 4608) {
    int i = bx - 4608;
    int half = t >> 7, tr = t & 127;
    int rowg = i * 2 + half;  // 0..1023 over (b,q)
    const float* qrow = qst + (size_t)rowg * EE;
    float4 qv = *(const float4*)&qrow[tr * 4];
    float4 wm4 = *(const float4*)&wmul[tr * 4];
    float4 wq4 = *(const float4*)&wqv[tr * 4];
    float m[4] = {qv.x * wm4.x, qv.y * wm4.y, qv.z * wm4.z, qv.w * wm4.w};
    bf16x4 h, l;
#pragma unroll
    for (int k = 0; k < 4; ++k) {
      bf16 hh = (bf16)m[k];
      h[k] = hh; l[k] = (bf16)(m[k] - (float)hh);
    }
    *(bf16x4*)&qmh[(size_t)rowg * EE + tr * 4] = h;
    *(bf16x4*)&qml[(size_t)rowg * EE + tr * 4] = l;
    float s = qv.x * wq4.x + qv.y * wq4.y + qv.z * wq4.z + qv.w * wq4.w;
#pragma unroll
    for (int off = 32; off; off >>= 1) s += __shfl_xor(s, off);
    if ((t & 63) == 0) r4[t >> 6] = s;
    __syncthreads();
    if (tr == 0) qw[rowg] = r4[half * 2] + r4[half * 2 + 1];
    return;
  }
  const float* src;
  bf16* dst;
  int R, C, idx;
  if (bx < 2048) {
    src = W1; dst = W1T; R = 2048; C = 1024; idx = bx;
  } else if (bx < 4096) {
    src = W2; dst = W2T; R = 1024; C = 2048; idx = bx - 2048;
  } else {
    int i = bx - 4096;
    int b = i >> 6; idx = i & 63;
    src = qst + (size_t)b * QQ * EE; dst = qT + (size_t)b * EE * QQ;
    R = 128; C = 512;
  }
  int ctiles = C >> 5;
  int by = idx / ctiles, cx = idx % ctiles;
  int tx = t & 31, ty = t >> 5;
#pragma unroll
  for (int rr = 0; rr < 4; ++rr)
    tile[ty + rr * 8][tx] = src[(size_t)(by * 32 + ty + rr * 8) * C + cx * 32 + tx];
  __syncthreads();
#pragma unroll
  for (int rr = 0; rr < 4; ++rr)
    dst[(size_t)(cx * 32 + ty + rr * 8) * R + by * 32 + tx] = (bf16)tile[tx][ty + rr * 8];
}

// ---------------------------------------------------------------------------
// fused_att: per (b = bid&7 [XCD-pin], 16 ctx rows). Unchanged.
// ---------------------------------------------------------------------------
__global__ __launch_bounds__(256) void fused_att_kernel(
    const float* __restrict__ ctx, const bf16* __restrict__ qmh,
    const bf16* __restrict__ qml, const bf16* __restrict__ qT,
    const float* __restrict__ wc, const float* __restrict__ qw,
    float* __restrict__ smax, bf16* __restrict__ att) {
  __shared__ __align__(16) char U[32768];
  __shared__ float wc_s[EE];
  __shared__ float qw_s[QQ];
  __shared__ float cw_s[16];
  __shared__ bf16 P_lds[16][136];
  int bid = blockIdx.x;
  int t = threadIdx.x;
  int b = bid & 7;             // XCD pin
  int m0 = (bid >> 3) * 16;
  bf16* Bh = (bf16*)(U);                       // 2 bufs x 128x32 (8192B each)
  bf16* Bl = (bf16*)(U + 16384);               // 2 bufs
  float(*sim_s)[132] = (float(*)[132])(U);     // overlays B bufs (post-loop)
  bf16* c2q_lds = (bf16*)(U);                  // overlays (stage 2)
  for (int i = t; i < EE; i += 256) wc_s[i] = wc[i];
  if (t < QQ) qw_s[t] = qw[b * QQ + t];
  int wv = t >> 6, ln = t & 63;
  int rl = ln & 15, kq = ln >> 4;
  const float* Ag = ctx + ((size_t)b * CC + m0) * EE;
  const bf16* Bhg = qmh + (size_t)b * QQ * EE;
  const bf16* Blg = qml + (size_t)b * QQ * EE;
#pragma unroll
  for (int r = 0; r < 2; ++r) {
    int fb = (r * 4 + wv) * 1024 + ln * 16;
    int row = fb >> 6;
    int cq = ((fb >> 4) & 3) ^ ((row >> 1) & 3);
    async_copy16(Bhg + (size_t)row * EE + cq * 8, (char*)Bh + fb);
    async_copy16(Blg + (size_t)row * EE + cq * 8, (char*)Bl + fb);
  }
  const float* apb = Ag + (size_t)rl * EE + kq * 8;
  float4 a0 = *(const float4*)apb;
  float4 a1 = *(const float4*)(apb + 4);
  __syncthreads();
  f32x4 acc[2] = {};
  float cwp = 0.f;
  for (int it = 0; it < 16; ++it) {
    int k0 = it * 32;
    int cur = (it & 1) * 8192;
    int nxt = 8192 - cur;
    if (it + 1 < 16) {
#pragma unroll
      for (int r = 0; r < 2; ++r) {
        int fb = (r * 4 + wv) * 1024 + ln * 16;
        int row = fb >> 6;
        int cq = ((fb >> 4) & 3) ^ ((row >> 1) & 3);
        async_copy16(Bhg + (size_t)row * EE + k0 + 32 + cq * 8,
                     (char*)Bh + nxt + fb);
        async_copy16(Blg + (size_t)row * EE + k0 + 32 + cq * 8,
                     (char*)Bl + nxt + fb);
      }
    }
    float4 na0, na1;
    if (it + 1 < 16) {
      const float* ap2 = Ag + (size_t)rl * EE + k0 + 32 + kq * 8;
      na0 = *(const float4*)ap2;
      na1 = *(const float4*)(ap2 + 4);
    }
    float av[8] = {a0.x, a0.y, a0.z, a0.w, a1.x, a1.y, a1.z, a1.w};
    bf16x8 ah, al;
#pragma unroll
    for (int k = 0; k < 8; ++k) {
      bf16 hh = (bf16)av[k];
      ah[k] = hh; al[k] = (bf16)(av[k] - (float)hh);
    }
    if (wv == 0) {
#pragma unroll
      for (int k = 0; k < 8; ++k) cwp += av[k] * wc_s[k0 + kq * 8 + k];
    }
    bf16x8 bh[2], bl[2];
#pragma unroll
    for (int j = 0; j < 2; ++j) {
      int r = wv * 32 + j * 16 + rl;
      int sl = (kq ^ ((r >> 1) & 3)) * 8;
      bh[j] = *(const bf16x8*)((const char*)Bh + cur + (r * 32 + sl) * 2);
      bl[j] = *(const bf16x8*)((const char*)Bl + cur + (r * 32 + sl) * 2);
    }
#pragma unroll
    for (int j = 0; j < 2; ++j) {
      acc[j] = __builtin_amdgcn_mfma_f32_16x16x32_bf16(ah, bh[j], acc[j], 0, 0, 0);
      acc[j] = __builtin_amdgcn_mfma_f32_16x16x32_bf16(ah, bl[j], acc[j], 0, 0, 0);
      acc[j] = __builtin_amdgcn_mfma_f32_16x16x32_bf16(al, bh[j], acc[j], 0, 0, 0);
    }
    a0 = na0; a1 = na1;
    __syncthreads();
  }
  if (wv == 0) {
    float s = cwp;
    s += __shfl_xor(s, 16);
    s += __shfl_xor(s, 32);
    if (ln < 16) cw_s[ln] = s;
  }
#pragma unroll
  for (int j = 0; j < 2; ++j) {
    int col = wv * 32 + j * 16 + rl;
    float qv = qw_s[col];
    int rbase = kq * 4;
#pragma unroll
    for (int r = 0; r < 4; ++r) sim_s[rbase + r][col] = acc[j][r] + qv;
  }
  __syncthreads();
  {
    int row = t >> 4, cb = t & 15;
    float v[8];
    float mx = -3.4e38f;
#pragma unroll
    for (int k = 0; k < 8; ++k) {
      v[k] = sim_s[row][cb + 16 * k];
      mx = fmaxf(mx, v[k]);
    }
    mx = fmaxf(mx, __shfl_xor(mx, 1));
    mx = fmaxf(mx, __shfl_xor(mx, 2));
    mx = fmaxf(mx, __shfl_xor(mx, 4));
    mx = fmaxf(mx, __shfl_xor(mx, 8));
    float sm = 0.f;
#pragma unroll
    for (int k = 0; k < 8; ++k) { v[k] = __expf(v[k] - mx); sm += v[k]; }
    sm += __shfl_xor(sm, 1);
    sm += __shfl_xor(sm, 2);
    sm += __shfl_xor(sm, 4);
    sm += __shfl_xor(sm, 8);
    float inv = 1.0f / sm;
#pragma unroll
    for (int k = 0; k < 8; ++k) P_lds[row][cb + 16 * k] = (bf16)(v[k] * inv);
    if (cb == 0) smax[b * CC + m0 + row] = mx + cw_s[row];
  }
  __syncthreads();
  f32x4 acc2[8] = {};
  const bf16* qTb = qT + (size_t)b * EE * QQ;
#pragma unroll
  for (int kk = 0; kk < 4; ++kk) {
    bf16x8 af2;
    {
      bf16x4 lo = *(const bf16x4*)&P_lds[rl][kk * 32 + kq * 8];
      bf16x4 hi = *(const bf16x4*)&P_lds[rl][kk * 32 + kq * 8 + 4];
      af2[0] = lo[0]; af2[1] = lo[1]; af2[2] = lo[2]; af2[3] = lo[3];
      af2[4] = hi[0]; af2[5] = hi[1]; af2[6] = hi[2]; af2[7] = hi[3];
    }
#pragma unroll
    for (int j = 0; j < 8; ++j) {
      int n = wv * 128 + j * 16 + rl;
      bf16x8 bfr = *(const bf16x8*)&qTb[(size_t)n * QQ + kk * 32 + kq * 8];
      acc2[j] = __builtin_amdgcn_mfma_f32_16x16x32_bf16(af2, bfr, acc2[j], 0, 0, 0);
    }
  }
#pragma unroll
  for (int j = 0; j < 8; ++j) {
    int col = wv * 128 + j * 16 + rl;
    int rbase = kq * 4;
#pragma unroll
    for (int r = 0; r < 4; ++r)
      c2q_lds[(size_t)(rbase + r) * 520 + col] = (bf16)acc2[j][r];
  }
  __syncthreads();
  {
    int row = t >> 4, tc = t & 15;
    const float* crow = ctx + ((size_t)(b * CC + m0 + row)) * EE;
    bf16* arow_p = att + ((size_t)(b * CC + m0 + row)) * FOURE;
#pragma unroll
    for (int cc = 0; cc < 4; ++cc) {
      int col = cc * 128 + tc * 8;
      bf16x8 q8 = *(const bf16x8*)&c2q_lds[(size_t)row * 520 + col];
      float4 v0 = *(const float4*)&crow[col];
      float4 v1 = *(const float4*)&crow[col + 4];
      float cv[8] = {v0.x, v0.y, v0.z, v0.w, v1.x, v1.y, v1.z, v1.w};
      bf16x8 o0, o2;
#pragma unroll
      for (int k = 0; k < 8; ++k) {
        o0[k] = (bf16)cv[k];
        o2[k] = (bf16)(cv[k] * (float)q8[k]);
      }
      *(bf16x8*)&arow_p[col] = o0;
      *(bf16x8*)&arow_p[EE + col] = q8;
      *(bf16x8*)&arow_p[2 * EE + col] = o2;
    }
  }
}

// ---------------------------------------------------------------------------
// q2c: fused softmax over c. Grid 256 (1-D), batch->XCD pinned. Unchanged.
// ---------------------------------------------------------------------------
__global__ __launch_bounds__(256) void q2c_kernel(
    const float* __restrict__ ctx, const float* __restrict__ smax,
    float* __restrict__ q2c) {
  int b = blockIdx.x & 7, ch = blockIdx.x >> 3;
  int t = threadIdx.x;
  __shared__ float red4m[4], red4s[4];
  __shared__ float w_s[32];
  float v[4];
  float mx = -3.4e38f;
#pragma unroll
  for (int i = 0; i < 4; ++i) {
    v[i] = smax[b * CC + i * 256 + t];
    mx = fmaxf(mx, v[i]);
  }
#pragma unroll
  for (int off = 32; off; off >>= 1) mx = fmaxf(mx, __shfl_xor(mx, off));
  if ((t & 63) == 0) red4m[t >> 6] = mx;
  __syncthreads();
  mx = fmaxf(fmaxf(red4m[0], red4m[1]), fmaxf(red4m[2], red4m[3]));
  float sm = 0.f;
#pragma unroll
  for (int i = 0; i < 4; ++i) sm += __expf(v[i] - mx);
#pragma unroll
  for (int off = 32; off; off >>= 1) sm += __shfl_xor(sm, off);
  if ((t & 63) == 0) red4s[t >> 6] = sm;
  __syncthreads();
  float inv = 1.0f / (red4s[0] + red4s[1] + red4s[2] + red4s[3]);
  if (t < 32) w_s[t] = __expf(smax[b * CC + ch * 32 + t] - mx) * inv;
  __syncthreads();
  int e = t * 2;
  const float* cb = ctx + ((size_t)b * CC + ch * 32) * EE;
  float a0 = 0.f, a1 = 0.f;
#pragma unroll 8
  for (int r = 0; r < 32; ++r) {
    float2 vv = *(const float2*)&cb[(size_t)r * EE + e];
    float w = w_s[r];
    a0 += w * vv.x;
    a1 += w * vv.y;
  }
  atomicAdd(&q2c[b * EE + e], a0);
  atomicAdd(&q2c[b * EE + e + 1], a1);
}

// ---------------------------------------------------------------------------
// att part 3: att[:, 3E:4E] = ctx * q2c[b]. Batch->XCD pinned. Unchanged.
// ---------------------------------------------------------------------------
__global__ __launch_bounds__(256) void att3_kernel(
    const float* __restrict__ ctx, const float* __restrict__ q2c,
    bf16* __restrict__ att) {
  int b = blockIdx.x & 7;
  int inner = (blockIdx.x >> 3) * 256 + threadIdx.x;
  int row = b * CC + (inner >> 6);
  int e = (inner & 63) * 8;
  float4 v0 = *(const float4*)&ctx[(size_t)row * EE + e];
  float4 v1 = *(const float4*)&ctx[(size_t)row * EE + e + 4];
  float4 g0 = *(const float4*)&q2c[b * EE + e];
  float4 g1 = *(const float4*)&q2c[b * EE + e + 4];
  bf16x8 o;
  o[0] = (bf16)(v0.x * g0.x); o[1] = (bf16)(v0.y * g0.y);
  o[2] = (bf16)(v0.z * g0.z); o[3] = (bf16)(v0.w * g0.w);
  o[4] = (bf16)(v1.x * g1.x); o[5] = (bf16)(v1.y * g1.y);
  o[6] = (bf16)(v1.z * g1.z); o[7] = (bf16)(v1.w * g1.w);
  *(bf16x8*)&att[(size_t)row * FOURE + 3 * EE + e] = o;
}

// ---------------------------------------------------------------------------
// FUSED MLP (XCD-pinned panels): GEMM1 (256x128, 2-phase ring-3) ->
// per-panel flag sync -> GEMM2 (256x256, 8-phase). Grid 256 = 1 block/CU.
// R8 ERRATA FIX: panel->XCD pinning. bid%8 = XCD; mt = xcd*4 + (local>>3)
// so ALL 8 blocks sharing an A-panel (attA rows, then hbuf rows) sit on the
// SAME XCD -> panel fetched once into that L2 and reused 8x (R8's
// mt=bid>>3 spread peers over 8 XCDs -> FETCH 201MB vs 58MB, latency-bound).
// Flag spins are also same-L2 now. K-loop bodies verbatim.
// ---------------------------------------------------------------------------
__global__ __launch_bounds__(512, 2) void gemm_fused_kernel(
    const bf16* __restrict__ attA, const bf16* __restrict__ W1T,
    const float* __restrict__ b1, bf16* __restrict__ hbuf,
    const bf16* __restrict__ W2T, const float* __restrict__ b2,
    const float* __restrict__ mask, float* __restrict__ out,
    unsigned* __restrict__ flags) {
  __shared__ __align__(16) char LDSU[147456];
  int bid = blockIdx.x;
  int t = threadIdx.x, wv = t >> 6, ln = t & 63;
  int rl = ln & 15, kq = ln >> 4;
  int xcd = bid & 7, local = bid >> 3;
  int mt = xcd * 4 + (local >> 3);   // panel 0..31, pinned to XCD mt>>2
  int ntb = local & 7;               // n-tile 0..7 (both phases)
  int m0 = mt << 8;

  // ================= phase 1: GEMM1 tile, K=2048, N=1024 ==================
  {
    const int K = 2048, N = 1024;
    int n0 = ntb << 7;
    int wm = wv >> 1, wn = wv & 1;
    int NT = K >> 6;
    auto As = [&](int buf) { return (bf16*)(LDSU + buf * 32768); };
    auto Bs = [&](int buf) { return (bf16*)(LDSU + 98304 + buf * 16384); };
    auto stageA = [&](int buf, int kt, int r) {
      int k0 = kt << 6;
      int fb = r * 8192 + t * 16;
      int row = fb >> 7;
      int q = ((fb >> 4) & 7) ^ (row & 7);
      async_copy16(attA + (size_t)(m0 + row) * K + k0 + q * 8,
                   (char*)As(buf) + fb);
    };
    auto stageB = [&](int buf, int kt, int r) {
      int k0 = kt << 6;
      int fb = r * 8192 + t * 16;
      int row = fb >> 7;
      int q = ((fb >> 4) & 7) ^ (row & 7);
      async_copy16(W1T + (size_t)(n0 + row) * K + k0 + q * 8,
                   (char*)Bs(buf) + fb);
    };
#pragma unroll
    for (int r = 0; r < 4; ++r) stageA(0, 0, r);
#pragma unroll
    for (int r = 0; r < 2; ++r) stageB(0, 0, r);
#pragma unroll
    for (int r = 0; r < 4; ++r) stageA(1, 1, r);
#pragma unroll
    for (int r = 0; r < 2; ++r) stageB(1, 1, r);
    asm volatile("s_waitcnt vmcnt(6)" ::: "memory");
    __builtin_amdgcn_s_barrier();

    f32x4 acc[4][4] = {};
    int cur = 0;
    for (int kt = 0; kt < NT; ++kt) {
      const bf16* Ab = As(cur);
      const bf16* Bb = Bs(cur);
      int nxt = cur + 2; if (nxt >= 3) nxt -= 3;
      bool pf = (kt + 2) < NT;
      bf16x8 af0[2][2], bfr[2][4];
#pragma unroll
      for (int ks = 0; ks < 2; ++ks) {
        int c = ks * 4 + kq;
#pragma unroll
        for (int i = 0; i < 2; ++i) {
          int row = wm * 64 + i * 16 + rl;
          af0[ks][i] = *(const bf16x8*)&Ab[row * 64 + ((c ^ (row & 7)) * 8)];
        }
#pragma unroll
        for (int j = 0; j < 4; ++j) {
          int row = wn * 64 + j * 16 + rl;
          bfr[ks][j] = *(const bf16x8*)&Bb[row * 64 + ((c ^ (row & 7)) * 8)];
        }
      }
      if (pf) { stageA(nxt, kt + 2, 0); stageA(nxt, kt + 2, 1); stageA(nxt, kt + 2, 2); }
      __builtin_amdgcn_s_barrier();
      asm volatile("s_waitcnt lgkmcnt(0)" ::: "memory");
      __builtin_amdgcn_sched_barrier(0);
      __builtin_amdgcn_s_setprio(1);
#pragma unroll
      for (int ks = 0; ks < 2; ++ks)
#pragma unroll
        for (int i = 0; i < 2; ++i)
#pragma unroll
          for (int j = 0; j < 4; ++j)
            acc[i][j] = __builtin_amdgcn_mfma_f32_16x16x32_bf16(
                af0[ks][i], bfr[ks][j], acc[i][j], 0, 0, 0);
      __builtin_amdgcn_s_setprio(0);
      __builtin_amdgcn_s_barrier();
      bf16x8 af1[2][2];
#pragma unroll
      for (int ks = 0; ks < 2; ++ks) {
        int c = ks * 4 + kq;
#pragma unroll
        for (int i = 0; i < 2; ++i) {
          int row = wm * 64 + (i + 2) * 16 + rl;
          af1[ks][i] = *(const bf16x8*)&Ab[row * 64 + ((c ^ (row & 7)) * 8)];
        }
      }
      if (pf) { stageA(nxt, kt + 2, 3); stageB(nxt, kt + 2, 0); stageB(nxt, kt + 2, 1); }
      __builtin_amdgcn_s_barrier();
      asm volatile("s_waitcnt lgkmcnt(0)" ::: "memory");
      __builtin_amdgcn_sched_barrier(0);
      __builtin_amdgcn_s_setprio(1);
#pragma unroll
      for (int ks = 0; ks < 2; ++ks)
#pragma unroll
        for (int i = 0; i < 2; ++i)
#pragma unroll
          for (int j = 0; j < 4; ++j)
            acc[i + 2][j] = __builtin_amdgcn_mfma_f32_16x16x32_bf16(
                af1[ks][i], bfr[ks][j], acc[i + 2][j], 0, 0, 0);
      __builtin_amdgcn_s_setprio(0);
      if (kt + 1 < NT) {
        if (pf) asm volatile("s_waitcnt vmcnt(6)" ::: "memory");
        else    asm volatile("s_waitcnt vmcnt(0)" ::: "memory");
        __builtin_amdgcn_s_barrier();
      }
      cur += 1; if (cur >= 3) cur -= 3;
    }
    // epilogue -> hbuf bf16, mask, no relu; write-coalesced
    float bv4[4];
#pragma unroll
    for (int j = 0; j < 4; ++j) bv4[j] = b1[n0 + wn * 64 + j * 16 + rl];
#pragma unroll
    for (int i = 0; i < 4; ++i) {
      int rbase = m0 + wm * 64 + i * 16 + (kq << 2);
#pragma unroll
      for (int r = 0; r < 4; ++r) {
        int row = rbase + r;
        float mk = mask[row];
#pragma unroll
        for (int j = 0; j < 4; ++j) {
          int col = n0 + wn * 64 + j * 16 + rl;
          float v = acc[i][j][r] + bv4[j];
          v *= mk;
          hbuf[(size_t)row * N + col] = (bf16)v;
        }
      }
    }
  }

  // ---- publish panel tile; wait for the panel's 8 producers ----
  __threadfence();          // device-scope: hbuf stores visible before flag
  __syncthreads();
  if (t == 0) {
    __hip_atomic_fetch_add(&flags[mt], 1u, __ATOMIC_RELEASE,
                           __HIP_MEMORY_SCOPE_AGENT);
    while (__hip_atomic_load(&flags[mt], __ATOMIC_ACQUIRE,
                             __HIP_MEMORY_SCOPE_AGENT) < 8u)
      __builtin_amdgcn_s_sleep(2);
  }
  __syncthreads();

  // ================= phase 2: GEMM2 tile, K=1024, N=2048 ==================
  {
    const int K = 1024, N = 2048;
    int n0 = ntb << 8;
    int wm = wv >> 2, wn = wv & 3;
    int NT = K >> 6;
    int chunk = t & 7;
    auto As2 = [&](int buf) { return (bf16*)(LDSU + buf * 32768); };
    auto Bs2 = [&](int buf) { return (bf16*)(LDSU + 65536 + buf * 32768); };
    auto stage = [&](int buf, int k1, int arr, int half, int r) {
      int fb = r * 8192 + t * 16;
      int phys = half * 128 + (fb >> 7);
      int q = chunk ^ (phys & 7);
      if (arr == 0) {
        int lg = ((phys >> 6) & 1) * 128 + (phys >> 7) * 64 + (phys & 63);
        async_copy16(hbuf + (size_t)(m0 + lg) * K + k1 + q * 8,
                     (char*)As2(buf) + half * 16384 + fb);
      } else {
        int lg = ((phys >> 5) & 3) * 64 + (phys >> 7) * 32 + (phys & 31);
        async_copy16(W2T + (size_t)(n0 + lg) * K + k1 + q * 8,
                     (char*)Bs2(buf) + half * 16384 + fb);
      }
    };
    auto ldA = [&](const bf16* Ab, int i, int ks) {
      int pr = (i >> 2) * 128 + wm * 64 + (i & 3) * 16 + rl;
      return *(const bf16x8*)&Ab[pr * 64 + (((ks * 4 + kq) ^ (pr & 7)) * 8)];
    };
    auto ldB = [&](const bf16* Bb, int j, int ks) {
      int pr = (j >> 1) * 128 + wn * 32 + (j & 1) * 16 + rl;
      return *(const bf16x8*)&Bb[pr * 64 + (((ks * 4 + kq) ^ (pr & 7)) * 8)];
    };

    stage(0, 0, 0, 0, 0); stage(0, 0, 0, 0, 1);
    stage(0, 0, 1, 0, 0); stage(0, 0, 1, 0, 1);
    stage(0, 0, 0, 1, 0); stage(0, 0, 0, 1, 1);
    stage(0, 0, 1, 1, 0); stage(0, 0, 1, 1, 1);
    stage(1, 64, 0, 0, 0); stage(1, 64, 0, 0, 1);
    stage(1, 64, 1, 0, 0); stage(1, 64, 1, 0, 1);
    asm volatile("s_waitcnt vmcnt(4)" ::: "memory");
    __builtin_amdgcn_s_barrier();

    f32x4 acc[8][4] = {};
    bf16x8 aX[4][2], bL[2][2], bH[2][2];
    int NI = NT >> 1;
    for (int it = 0; it < NI; ++it) {
      const bf16* A0 = As2(0);
      const bf16* B0 = Bs2(0);
      const bf16* A1 = As2(1);
      const bf16* B1 = Bs2(1);
      int t1k = ((it << 1) + 1) << 6;
      int t2k = ((it << 1) + 2) << 6;
      int t3k = ((it << 1) + 3) << 6;
      bool s2 = ((it << 1) + 2) < NT;
      bool s3 = ((it << 1) + 3) < NT;
      bool last = (it == NI - 1);

      // ---- p1 ----
#pragma unroll
      for (int i = 0; i < 4; ++i) { aX[i][0] = ldA(A0, i, 0); aX[i][1] = ldA(A0, i, 1); }
#pragma unroll
      for (int j = 0; j < 2; ++j) { bL[j][0] = ldB(B0, j, 0); bL[j][1] = ldB(B0, j, 1); }
      stage(1, t1k, 0, 1, 0); stage(1, t1k, 0, 1, 1);
      asm volatile("s_waitcnt lgkmcnt(8)" ::: "memory");
      __builtin_amdgcn_s_barrier();
      asm volatile("s_waitcnt lgkmcnt(0)" ::: "memory");
      __builtin_amdgcn_sched_barrier(0);
      __builtin_amdgcn_s_setprio(1);
#pragma unroll
      for (int ks = 0; ks < 2; ++ks)
#pragma unroll
        for (int i = 0; i < 4; ++i)
#pragma unroll
          for (int j = 0; j < 2; ++j)
            acc[i][j] = __builtin_amdgcn_mfma_f32_16x16x32_bf16(
                aX[i][ks], bL[j][ks], acc[i][j], 0, 0, 0);
      __builtin_amdgcn_s_setprio(0);
      __builtin_amdgcn_s_barrier();
      // ---- p2 ----
#pragma unroll
      for (int j = 0; j < 2; ++j) { bH[j][0] = ldB(B0, j + 2, 0); bH[j][1] = ldB(B0, j + 2, 1); }
      stage(1, t1k, 1, 1, 0); stage(1, t1k, 1, 1, 1);
      __builtin_amdgcn_s_barrier();
      asm volatile("s_waitcnt lgkmcnt(0)" ::: "memory");
      __builtin_amdgcn_sched_barrier(0);
      __builtin_amdgcn_s_setprio(1);
#pragma unroll
      for (int ks = 0; ks < 2; ++ks)
#pragma unroll
        for (int i = 0; i < 4; ++i)
#pragma unroll
          for (int j = 0; j < 2; ++j)
            acc[i][j + 2] = __builtin_amdgcn_mfma_f32_16x16x32_bf16(
                aX[i][ks], bH[j][ks], acc[i][j + 2], 0, 0, 0);
      __builtin_amdgcn_s_setprio(0);
      __builtin_amdgcn_s_barrier();
      // ---- p3 ----
#pragma unroll
      for (int i = 0; i < 4; ++i) { aX[i][0] = ldA(A0, i + 4, 0); aX[i][1] = ldA(A0, i + 4, 1); }
      if (s2) { stage(0, t2k, 0, 0, 0); stage(0, t2k, 0, 0, 1); }
      __builtin_amdgcn_s_barrier();
      asm volatile("s_waitcnt lgkmcnt(0)" ::: "memory");
      __builtin_amdgcn_sched_barrier(0);
      __builtin_amdgcn_s_setprio(1);
#pragma unroll
      for (int ks = 0; ks < 2; ++ks)
#pragma unroll
        for (int i = 0; i < 4; ++i)
#pragma unroll
          for (int j = 0; j < 2; ++j)
            acc[i + 4][j] = __builtin_amdgcn_mfma_f32_16x16x32_bf16(
                aX[i][ks], bL[j][ks], acc[i + 4][j], 0, 0, 0);
      __builtin_amdgcn_s_setprio(0);
      __builtin_amdgcn_s_barrier();
      // ---- p4 ----
      if (s2) { stage(0, t2k, 1, 0, 0); stage(0, t2k, 1, 0, 1); }
      __builtin_amdgcn_s_barrier();
      __builtin_amdgcn_s_setprio(1);
#pragma unroll
      for (int ks = 0; ks < 2; ++ks)
#pragma unroll
        for (int i = 0; i < 4; ++i)
#pragma unroll
          for (int j = 0; j < 2; ++j)
            acc[i + 4][j + 2] = __builtin_amdgcn_mfma_f32_16x16x32_bf16(
                aX[i][ks], bH[j][ks], acc[i + 4][j + 2], 0, 0, 0);
      __builtin_amdgcn_s_setprio(0);
      if (last) asm volatile("s_waitcnt vmcnt(0)" ::: "memory");
      else      asm volatile("s_waitcnt vmcnt(4)" ::: "memory");
      __builtin_amdgcn_s_barrier();
      // ---- p5 ----
#pragma unroll
      for (int i = 0; i < 4; ++i) { aX[i][0] = ldA(A1, i, 0); aX[i][1] = ldA(A1, i, 1); }
#pragma unroll
      for (int j = 0; j < 2; ++j) { bL[j][0] = ldB(B1, j, 0); bL[j][1] = ldB(B1, j, 1); }
      if (s2) { stage(0, t2k, 0, 1, 0); stage(0, t2k, 0, 1, 1); }
      asm volatile("s_waitcnt lgkmcnt(8)" ::: "memory");
      __builtin_amdgcn_s_barrier();
      asm volatile("s_waitcnt lgkmcnt(0)" ::: "memory");
      __builtin_amdgcn_sched_barrier(0);
      __builtin_amdgcn_s_setprio(1);
#pragma unroll
      for (int ks = 0; ks < 2; ++ks)
#pragma unroll
        for (int i = 0; i < 4; ++i)
#pragma unroll
          for (int j = 0; j < 2; ++j)
            acc[i][j] = __builtin_amdgcn_mfma_f32_16x16x32_bf16(
                aX[i][ks], bL[j][ks], acc[i][j], 0, 0, 0);
      __builtin_amdgcn_s_setprio(0);
      __builtin_amdgcn_s_barrier();
      // ---- p6 ----
#pragma unroll
      for (int j = 0; j < 2; ++j) { bH[j][0] = ldB(B1, j + 2, 0); bH[j][1] = ldB(B1, j + 2, 1); }
      if (s2) { stage(0, t2k, 1, 1, 0); stage(0, t2k, 1, 1, 1); }
      __builtin_amdgcn_s_barrier();
      asm volatile("s_waitcnt lgkmcnt(0)" ::: "memory");
      __builtin_amdgcn_sched_barrier(0);
      __builtin_amdgcn_s_setprio(1);
#pragma unroll
      for (int ks = 0; ks < 2; ++ks)
#pragma unroll
        for (int i = 0; i < 4; ++i)
#pragma unroll
          for (int j = 0; j < 2; ++j)
            acc[i][j + 2] = __builtin_amdgcn_mfma_f32_16x16x32_bf16(
                aX[i][ks], bH[j][ks], acc[i][j + 2], 0, 0, 0);
      __builtin_amdgcn_s_setprio(0);
      __builtin_amdgcn_s_barrier();
      // ---- p7 ----
#pragma unroll
      for (int i = 0; i < 4; ++i) { aX[i][0] = ldA(A1, i + 4, 0); aX[i][1] = ldA(A1, i + 4, 1); }
      if (s3) { stage(1, t3k, 0, 0, 0); stage(1, t3k, 0, 0, 1); }
      __builtin_amdgcn_s_barrier();
      asm volatile("s_waitcnt lgkmcnt(0)" ::: "memory");
      __builtin_amdgcn_sched_barrier(0);
      __builtin_amdgcn_s_setprio(1);
#pragma unroll
      for (int ks = 0; ks < 2; ++ks)
#pragma unroll
        for (int i = 0; i < 4; ++i)
#pragma unroll
          for (int j = 0; j < 2; ++j)
            acc[i + 4][j] = __builtin_amdgcn_mfma_f32_16x16x32_bf16(
                aX[i][ks], bL[j][ks], acc[i + 4][j], 0, 0, 0);
      __builtin_amdgcn_s_setprio(0);
      __builtin_amdgcn_s_barrier();
      // ---- p8 ----
      if (s3) { stage(1, t3k, 1, 0, 0); stage(1, t3k, 1, 0, 1); }
      __builtin_amdgcn_s_barrier();
      __builtin_amdgcn_s_setprio(1);
#pragma unroll
      for (int ks = 0; ks < 2; ++ks)
#pragma unroll
        for (int i = 0; i < 4; ++i)
#pragma unroll
          for (int j = 0; j < 2; ++j)
            acc[i + 4][j + 2] = __builtin_amdgcn_mfma_f32_16x16x32_bf16(
                aX[i][ks], bH[j][ks], acc[i + 4][j + 2], 0, 0, 0);
      __builtin_amdgcn_s_setprio(0);
      if (!last) {
        asm volatile("s_waitcnt vmcnt(4)" ::: "memory");
        __builtin_amdgcn_s_barrier();
      }
    }

    // epilogue -> out f32, relu, mask; write-coalesced
    float bv4[4];
#pragma unroll
    for (int j = 0; j < 4; ++j) bv4[j] = b2[n0 + wn * 64 + j * 16 + rl];
#pragma unroll
    for (int i = 0; i < 8; ++i) {
      int rbase = m0 + wm * 128 + i * 16 + (kq << 2);
#pragma unroll
      for (int r = 0; r < 4; ++r) {
        int row = rbase + r;
        float mk = mask[row];
#pragma unroll
        for (int j = 0; j < 4; ++j) {
          int col = n0 + wn * 64 + j * 16 + rl;
          float v = acc[i][j][r] + bv4[j];
          v *= mk;
          v = fmaxf(v, 0.f);
          out[(size_t)row * N + col] = v;
        }
      }
    }
  }
}

// ---------------------------------------------------------------------------
// launcher — 5 kernels (GEMM1+GEMM2 fused; flags zeroed in prep)
// ---------------------------------------------------------------------------
extern "C" void kernel_launch(void* const* d_in, const int* in_sizes, int n_in,
                              void* d_out, int out_size, void* d_ws, size_t ws_size,
                              hipStream_t stream) {
  const float* ctx = (const float*)d_in[0];
  const float* qst = (const float*)d_in[1];
  const float* mask = (const float*)d_in[2];
  const float* wqv = (const float*)d_in[3];
  const float* wcv = (const float*)d_in[4];
  const float* wmul = (const float*)d_in[5];
  const float* W1 = (const float*)d_in[6];
  const float* b1 = (const float*)d_in[7];
  const float* W2 = (const float*)d_in[8];
  const float* b2 = (const float*)d_in[9];
  float* out = (float*)d_out;
  char* ws = (char*)d_ws;

  bf16* att = (bf16*)(ws);                  // 33554432
  bf16* hbuf = (bf16*)(ws + 33554432);      // 16777216
  bf16* W1T = (bf16*)(ws + 50331648);       // 4194304
  bf16* W2T = (bf16*)(ws + 54525952);       // 4194304
  bf16* qT = (bf16*)(ws + 58720256);        // 1048576
  bf16* qmh = (bf16*)(ws + 59768832);       // 1048576
  bf16* qml = (bf16*)(ws + 60817408);       // 1048576
  float* smax = (float*)(ws + 61865984);    // 32768
  float* q2c = (float*)(ws + 61898752);     // 16384
  float* qw = (float*)(ws + 61915136);      // 4096
  unsigned* flags = (unsigned*)(ws + 61919232);  // 128

  prep_kernel<<<5121, 256, 0, stream>>>(W1, W2, qst, wmul, wqv,
                                        W1T, W2T, qT, qmh, qml, qw, q2c, flags);
  fused_att_kernel<<<512, 256, 0, stream>>>(ctx, qmh, qml, qT, wcv,
                                            qw, smax, att);
  q2c_kernel<<<256, 256, 0, stream>>>(ctx, smax, q2c);
  att3_kernel<<<2048, 256, 0, stream>>>(ctx, q2c, att);
  // fused MLP: h = (att@W1+b1)*mask -> out = relu((h@W2+b2)*mask)
  gemm_fused_kernel<<<256, 512, 0, stream>>>(att, W1T, b1, hbuf,
                                             W2T, b2, mask, out, flags);
}

// Round 10
// 215.109 us; speedup vs baseline: 1.4319x; 1.3564x over previous
//
#include <hip/hip_runtime.h>

typedef __bf16 bf16;
typedef __bf16 bf16x2 __attribute__((ext_vector_type(2)));
typedef __bf16 bf16x4 __attribute__((ext_vector_type(4)));
typedef __bf16 bf16x8 __attribute__((ext_vector_type(8)));
typedef float f32x4 __attribute__((ext_vector_type(4)));

#define AS1 __attribute__((address_space(1)))
#define AS3 __attribute__((address_space(3)))

__device__ __forceinline__ void async_copy16(const void* g, void* l) {
  // global -> LDS direct, 16B/lane; LDS dest = wave-uniform base + lane*16.
  __builtin_amdgcn_global_load_lds((const AS1 void*)g, (AS3 void*)l, 16, 0, 0);
}

#define BB 8
#define CC 1024
#define QQ 128
#define EE 512
#define HH 1024
#define FOURE 2048

// ---------------------------------------------------------------------------
// prep:
//  bx [0,2048):    W1 (2048x1024) -> W1T
//  bx [2048,4096): W2 (1024x2048) -> W2T
//  bx [4096,4608): question per-batch transpose -> qT
//  bx [4608,5120): qm = question*wmul -> bf16 hi/lo (qmh/qml) + qw row-dots
//  bx == 5120:     zero q2c
// ---------------------------------------------------------------------------
__global__ __launch_bounds__(256) void prep_kernel(
    const float* __restrict__ W1, const float* __restrict__ W2,
    const float* __restrict__ qst, const float* __restrict__ wmul,
    const float* __restrict__ wqv, bf16* __restrict__ W1T,
    bf16* __restrict__ W2T, bf16* __restrict__ qT,
    bf16* __restrict__ qmh, bf16* __restrict__ qml, float* __restrict__ qw,
    float* __restrict__ q2c) {
  __shared__ float tile[32][33];
  __shared__ float r4[4];
  int bx = blockIdx.x;
  int t = threadIdx.x;
  if (bx >= 5120) {
    for (int i = t; i < BB * EE; i += 256) q2c[i] = 0.f;
    return;
  }
  if (bx >= 4608) {
    int i = bx - 4608;
    int half = t >> 7, tr = t & 127;
    int rowg = i * 2 + half;  // 0..1023 over (b,q)
    const float* qrow = qst + (size_t)rowg * EE;
    float4 qv = *(const float4*)&qrow[tr * 4];
    float4 wm4 = *(const float4*)&wmul[tr * 4];
    float4 wq4 = *(const float4*)&wqv[tr * 4];
    float m[4] = {qv.x * wm4.x, qv.y * wm4.y, qv.z * wm4.z, qv.w * wm4.w};
    bf16x4 h, l;
#pragma unroll
    for (int k = 0; k < 4; ++k) {
      bf16 hh = (bf16)m[k];
      h[k] = hh; l[k] = (bf16)(m[k] - (float)hh);
    }
    *(bf16x4*)&qmh[(size_t)rowg * EE + tr * 4] = h;
    *(bf16x4*)&qml[(size_t)rowg * EE + tr * 4] = l;
    float s = qv.x * wq4.x + qv.y * wq4.y + qv.z * wq4.z + qv.w * wq4.w;
#pragma unroll
    for (int off = 32; off; off >>= 1) s += __shfl_xor(s, off);
    if ((t & 63) == 0) r4[t >> 6] = s;
    __syncthreads();
    if (tr == 0) qw[rowg] = r4[half * 2] + r4[half * 2 + 1];
    return;
  }
  const float* src;
  bf16* dst;
  int R, C, idx;
  if (bx < 2048) {
    src = W1; dst = W1T; R = 2048; C = 1024; idx = bx;
  } else if (bx < 4096) {
    src = W2; dst = W2T; R = 1024; C = 2048; idx = bx - 2048;
  } else {
    int i = bx - 4096;
    int b = i >> 6; idx = i & 63;
    src = qst + (size_t)b * QQ * EE; dst = qT + (size_t)b * EE * QQ;
    R = 128; C = 512;
  }
  int ctiles = C >> 5;
  int by = idx / ctiles, cx = idx % ctiles;
  int tx = t & 31, ty = t >> 5;
#pragma unroll
  for (int rr = 0; rr < 4; ++rr)
    tile[ty + rr * 8][tx] = src[(size_t)(by * 32 + ty + rr * 8) * C + cx * 32 + tx];
  __syncthreads();
#pragma unroll
  for (int rr = 0; rr < 4; ++rr)
    dst[(size_t)(cx * 32 + ty + rr * 8) * R + by * 32 + tx] = (bf16)tile[tx][ty + rr * 8];
}

// ---------------------------------------------------------------------------
// fused_att: per (b = bid&7 [XCD-pin], 16 ctx rows): sim (split-bf16 3-MFMA)
//   + qw/cw -> softmax over q in LDS -> P (LDS) -> c2q = P @ qT^T
//   -> att[:, 0:3E] = [ctx | c2q | ctx*c2q] with 256B-contiguous stores.
// Grid 512 (1-D), batch->XCD pinned: per-XCD working set ~2.6MB (L2-fit).
// ---------------------------------------------------------------------------
__global__ __launch_bounds__(256) void fused_att_kernel(
    const float* __restrict__ ctx, const bf16* __restrict__ qmh,
    const bf16* __restrict__ qml, const bf16* __restrict__ qT,
    const float* __restrict__ wc, const float* __restrict__ qw,
    float* __restrict__ smax, bf16* __restrict__ att) {
  int bid = blockIdx.x;
  int b = bid & 7;             // XCD pin: bid%8 == XCD id
  int m0 = (bid >> 3) * 16;
  // Union: stage1 {Ah,Al,Bh,Bl,sim_s} (26880B) / stage2 {c2q_lds} (16640B)
  __shared__ __align__(16) char U[26880];
  bf16* Ah = (bf16*)(U);                            // 16x32
  bf16* Al = (bf16*)(U + 1024);                     // 16x32
  bf16* Bh = (bf16*)(U + 2048);                     // 128x32
  bf16* Bl = (bf16*)(U + 10240);                    // 128x32
  float(*sim_s)[132] = (float(*)[132])(U + 18432);  // 16 x 132
  bf16* c2q_lds = (bf16*)(U);                       // 16 x 520 (stage 2)
  __shared__ float wc_s[EE];
  __shared__ float qw_s[QQ];
  __shared__ float cw_s[16];
  __shared__ bf16 P_lds[16][136];
  int t = threadIdx.x;
  for (int i = t; i < EE; i += 256) wc_s[i] = wc[i];
  if (t < QQ) qw_s[t] = qw[b * QQ + t];
  __syncthreads();
  int wv = t >> 6, ln = t & 63;
  int rl = ln & 15, kq = ln >> 4;
  f32x4 acc[2] = {};
  const float* Ag = ctx + ((size_t)b * CC + m0) * EE;
  const bf16* Bhg = qmh + (size_t)b * QQ * EE;
  const bf16* Blg = qml + (size_t)b * QQ * EE;
  int arow = t >> 4, ae = (t & 15) * 2;  // A: 2 f32/thread, 16 thr/row
  float cwp = 0.f;
  for (int k0 = 0; k0 < EE; k0 += 32) {
    {  // A stage: f32 float2 load, hi/lo repack, cw accumulation
      float2 v = *(const float2*)(Ag + (size_t)arow * EE + k0 + ae);
      cwp += v.x * wc_s[k0 + ae] + v.y * wc_s[k0 + ae + 1];
      bf16 h0 = (bf16)v.x, h1 = (bf16)v.y;
      bf16x2 h, l;
      h[0] = h0; h[1] = h1;
      l[0] = (bf16)(v.x - (float)h0);
      l[1] = (bf16)(v.y - (float)h1);
      int sl = ((ae >> 3) ^ ((arow >> 1) & 3)) * 8 + (ae & 7);
      *(bf16x2*)&Ah[arow * 32 + sl] = h;
      *(bf16x2*)&Al[arow * 32 + sl] = l;
    }
#pragma unroll
    for (int r = 0; r < 2; ++r) {  // B stage: async from precomputed qm hi/lo
      int fb = (r * 4 + wv) * 1024 + ln * 16;
      int row = fb >> 6;
      int cq = ((fb >> 4) & 3) ^ ((row >> 1) & 3);
      async_copy16(Bhg + (size_t)row * EE + k0 + cq * 8, (char*)Bh + fb);
      async_copy16(Blg + (size_t)row * EE + k0 + cq * 8, (char*)Bl + fb);
    }
    __syncthreads();
    bf16x8 ah, al, bh[2], bl[2];
    {
      int sl = (kq ^ ((rl >> 1) & 3)) * 8;
      ah = *(const bf16x8*)&Ah[rl * 32 + sl];
      al = *(const bf16x8*)&Al[rl * 32 + sl];
    }
#pragma unroll
    for (int j = 0; j < 2; ++j) {
      int r = wv * 32 + j * 16 + rl;
      int sl = (kq ^ ((r >> 1) & 3)) * 8;
      bh[j] = *(const bf16x8*)&Bh[r * 32 + sl];
      bl[j] = *(const bf16x8*)&Bl[r * 32 + sl];
    }
#pragma unroll
    for (int j = 0; j < 2; ++j) {
      acc[j] = __builtin_amdgcn_mfma_f32_16x16x32_bf16(ah, bh[j], acc[j], 0, 0, 0);
      acc[j] = __builtin_amdgcn_mfma_f32_16x16x32_bf16(ah, bl[j], acc[j], 0, 0, 0);
      acc[j] = __builtin_amdgcn_mfma_f32_16x16x32_bf16(al, bh[j], acc[j], 0, 0, 0);
    }
    __syncthreads();
  }
  // cw reduce over the 16 threads of each row
  {
    float s = cwp;
    s += __shfl_xor(s, 1); s += __shfl_xor(s, 2);
    s += __shfl_xor(s, 4); s += __shfl_xor(s, 8);
    if ((t & 15) == 0) cw_s[arow] = s;
  }
  // spill sim (+qw) to LDS
#pragma unroll
  for (int j = 0; j < 2; ++j) {
    int col = wv * 32 + j * 16 + rl;
    float qv = qw_s[col];
    int rbase = kq * 4;
#pragma unroll
    for (int r = 0; r < 4; ++r) sim_s[rbase + r][col] = acc[j][r] + qv;
  }
  __syncthreads();
  // softmax over q: 16 threads/row, 8 cols each
  {
    int row = t >> 4, cb = t & 15;
    float v[8];
    float mx = -3.4e38f;
#pragma unroll
    for (int k = 0; k < 8; ++k) {
      v[k] = sim_s[row][cb + 16 * k];
      mx = fmaxf(mx, v[k]);
    }
    mx = fmaxf(mx, __shfl_xor(mx, 1));
    mx = fmaxf(mx, __shfl_xor(mx, 2));
    mx = fmaxf(mx, __shfl_xor(mx, 4));
    mx = fmaxf(mx, __shfl_xor(mx, 8));
    float sm = 0.f;
#pragma unroll
    for (int k = 0; k < 8; ++k) { v[k] = __expf(v[k] - mx); sm += v[k]; }
    sm += __shfl_xor(sm, 1);
    sm += __shfl_xor(sm, 2);
    sm += __shfl_xor(sm, 4);
    sm += __shfl_xor(sm, 8);
    float inv = 1.0f / sm;
#pragma unroll
    for (int k = 0; k < 8; ++k) P_lds[row][cb + 16 * k] = (bf16)(v[k] * inv);
    if (cb == 0) smax[b * CC + m0 + row] = mx + cw_s[row];
  }
  __syncthreads();  // P ready; sim_s dead -> U reusable by c2q_lds
  // stage 2: c2q(16x512) = P(16x128) @ qT(512x128)^T ; wave wv -> 128 cols
  f32x4 acc2[8] = {};
  const bf16* qTb = qT + (size_t)b * EE * QQ;
#pragma unroll
  for (int kk = 0; kk < 4; ++kk) {
    bf16x8 af2;
    {
      bf16x4 lo = *(const bf16x4*)&P_lds[rl][kk * 32 + kq * 8];
      bf16x4 hi = *(const bf16x4*)&P_lds[rl][kk * 32 + kq * 8 + 4];
      af2[0] = lo[0]; af2[1] = lo[1]; af2[2] = lo[2]; af2[3] = lo[3];
      af2[4] = hi[0]; af2[5] = hi[1]; af2[6] = hi[2]; af2[7] = hi[3];
    }
#pragma unroll
    for (int j = 0; j < 8; ++j) {
      int n = wv * 128 + j * 16 + rl;
      bf16x8 bfr = *(const bf16x8*)&qTb[(size_t)n * QQ + kk * 32 + kq * 8];
      acc2[j] = __builtin_amdgcn_mfma_f32_16x16x32_bf16(af2, bfr, acc2[j], 0, 0, 0);
    }
  }
  // spill c2q frags to LDS (row-major, stride 520)
#pragma unroll
  for (int j = 0; j < 8; ++j) {
    int col = wv * 128 + j * 16 + rl;
    int rbase = kq * 4;
#pragma unroll
    for (int r = 0; r < 4; ++r)
      c2q_lds[(size_t)(rbase + r) * 520 + col] = (bf16)acc2[j][r];
  }
  __syncthreads();
  // att epilogue: 16 rows x 512 cols, parts 0..2; 16 lanes cover 256B contig.
  {
    int row = t >> 4, tc = t & 15;
    const float* crow = ctx + ((size_t)(b * CC + m0 + row)) * EE;
    bf16* arow_p = att + ((size_t)(b * CC + m0 + row)) * FOURE;
#pragma unroll
    for (int cc = 0; cc < 4; ++cc) {
      int col = cc * 128 + tc * 8;
      bf16x8 q8 = *(const bf16x8*)&c2q_lds[(size_t)row * 520 + col];
      float4 v0 = *(const float4*)&crow[col];
      float4 v1 = *(const float4*)&crow[col + 4];
      float cv[8] = {v0.x, v0.y, v0.z, v0.w, v1.x, v1.y, v1.z, v1.w};
      bf16x8 o0, o2;
#pragma unroll
      for (int k = 0; k < 8; ++k) {
        o0[k] = (bf16)cv[k];
        o2[k] = (bf16)(cv[k] * (float)q8[k]);
      }
      *(bf16x8*)&arow_p[col] = o0;
      *(bf16x8*)&arow_p[EE + col] = q8;
      *(bf16x8*)&arow_p[2 * EE + col] = o2;
    }
  }
}

// ---------------------------------------------------------------------------
// q2c with fused (redundant per-block) softmax over c. Grid 256 (1-D),
// batch->XCD pinned (b = bid&7): per-XCD ctx working set = 2 MB (L2-fit).
// atomicAdd into pre-zeroed q2c.
// ---------------------------------------------------------------------------
__global__ __launch_bounds__(256) void q2c_kernel(
    const float* __restrict__ ctx, const float* __restrict__ smax,
    float* __restrict__ q2c) {
  int b = blockIdx.x & 7, ch = blockIdx.x >> 3;
  int t = threadIdx.x;
  __shared__ float red[256];
  __shared__ float w_s[32];
  float v[4];
  float mx = -3.4e38f;
#pragma unroll
  for (int i = 0; i < 4; ++i) {
    v[i] = smax[b * CC + i * 256 + t];
    mx = fmaxf(mx, v[i]);
  }
  red[t] = mx;
  __syncthreads();
  for (int s = 128; s > 0; s >>= 1) {
    if (t < s) red[t] = fmaxf(red[t], red[t + s]);
    __syncthreads();
  }
  mx = red[0];
  __syncthreads();
  float sm = 0.f;
#pragma unroll
  for (int i = 0; i < 4; ++i) sm += __expf(v[i] - mx);
  red[t] = sm;
  __syncthreads();
  for (int s = 128; s > 0; s >>= 1) {
    if (t < s) red[t] += red[t + s];
    __syncthreads();
  }
  float inv = 1.0f / red[0];
  if (t < 32) w_s[t] = __expf(smax[b * CC + ch * 32 + t] - mx) * inv;
  __syncthreads();
  int e = t * 2;
  const float* cb = ctx + ((size_t)b * CC + ch * 32) * EE;
  float a0 = 0.f, a1 = 0.f;
#pragma unroll 8
  for (int r = 0; r < 32; ++r) {
    float2 vv = *(const float2*)&cb[(size_t)r * EE + e];
    float w = w_s[r];
    a0 += w * vv.x;
    a1 += w * vv.y;
  }
  atomicAdd(&q2c[b * EE + e], a0);
  atomicAdd(&q2c[b * EE + e + 1], a1);
}

// ---------------------------------------------------------------------------
// att part 3: att[:, 3E:4E] = ctx * q2c[b]  (BW-bound). Batch->XCD pinned.
// ---------------------------------------------------------------------------
__global__ __launch_bounds__(256) void att3_kernel(
    const float* __restrict__ ctx, const float* __restrict__ q2c,
    bf16* __restrict__ att) {
  int b = blockIdx.x & 7;
  int inner = (blockIdx.x >> 3) * 256 + threadIdx.x;  // (row_in_batch, e/8)
  int row = b * CC + (inner >> 6);
  int e = (inner & 63) * 8;
  float4 v0 = *(const float4*)&ctx[(size_t)row * EE + e];
  float4 v1 = *(const float4*)&ctx[(size_t)row * EE + e + 4];
  float4 g0 = *(const float4*)&q2c[b * EE + e];
  float4 g1 = *(const float4*)&q2c[b * EE + e + 4];
  bf16x8 o;
  o[0] = (bf16)(v0.x * g0.x); o[1] = (bf16)(v0.y * g0.y);
  o[2] = (bf16)(v0.z * g0.z); o[3] = (bf16)(v0.w * g0.w);
  o[4] = (bf16)(v1.x * g1.x); o[5] = (bf16)(v1.y * g1.y);
  o[6] = (bf16)(v1.z * g1.z); o[7] = (bf16)(v1.w * g1.w);
  *(bf16x8*)&att[(size_t)row * FOURE + 3 * EE + e] = o;
}

// ---------------------------------------------------------------------------
// GEMM1 kernel (frozen): tile 256x128, 2-phase, ring-3, wave 64x64.
// Panel peers share XCD via mt = g*8 + (sub&7). Write-coalesced epilogue.
// ---------------------------------------------------------------------------
template <int OUT_BF16, int RELU>
__global__ __launch_bounds__(512, 2) void gemm_bt_p2_kernel(
    const bf16* __restrict__ A, const bf16* __restrict__ Bt,
    const float* __restrict__ bias, const float* __restrict__ mask,
    void* __restrict__ Cout, int M, int N, int K) {
  __shared__ bf16 As[3][256 * 64];
  __shared__ bf16 Bs[3][128 * 64];
  int ntiles = N >> 7;
  int tiles_per_g = 8 * ntiles;
  int g = blockIdx.x / tiles_per_g, sub = blockIdx.x % tiles_per_g;
  int mt = g * 8 + (sub & 7), ntb = sub >> 3;
  int m0 = mt << 8, n0 = ntb << 7;
  int t = threadIdx.x, wv = t >> 6, ln = t & 63;
  int wm = wv >> 1, wn = wv & 1;
  int rl = ln & 15, kq = ln >> 4;
  int NT = K >> 6;

  auto stageA = [&](int buf, int kt, int r) {
    int k0 = kt << 6;
    int fb = r * 8192 + t * 16;
    int row = fb >> 7;
    int q = ((fb >> 4) & 7) ^ (row & 7);
    async_copy16(A + (size_t)(m0 + row) * K + k0 + q * 8, (char*)As[buf] + fb);
  };
  auto stageB = [&](int buf, int kt, int r) {
    int k0 = kt << 6;
    int fb = r * 8192 + t * 16;
    int row = fb >> 7;
    int q = ((fb >> 4) & 7) ^ (row & 7);
    async_copy16(Bt + (size_t)(n0 + row) * K + k0 + q * 8, (char*)Bs[buf] + fb);
  };

#pragma unroll
  for (int r = 0; r < 4; ++r) stageA(0, 0, r);
#pragma unroll
  for (int r = 0; r < 2; ++r) stageB(0, 0, r);
#pragma unroll
  for (int r = 0; r < 4; ++r) stageA(1, 1, r);
#pragma unroll
  for (int r = 0; r < 2; ++r) stageB(1, 1, r);
  asm volatile("s_waitcnt vmcnt(6)" ::: "memory");
  __builtin_amdgcn_s_barrier();

  f32x4 acc[4][4] = {};
  int cur = 0;
  for (int kt = 0; kt < NT; ++kt) {
    const bf16* Ab = As[cur];
    const bf16* Bb = Bs[cur];
    int nxt = cur + 2; if (nxt >= 3) nxt -= 3;
    bool pf = (kt + 2) < NT;
    bf16x8 af0[2][2], bfr[2][4];
#pragma unroll
    for (int ks = 0; ks < 2; ++ks) {
      int c = ks * 4 + kq;
#pragma unroll
      for (int i = 0; i < 2; ++i) {
        int row = wm * 64 + i * 16 + rl;
        af0[ks][i] = *(const bf16x8*)&Ab[row * 64 + ((c ^ (row & 7)) * 8)];
      }
#pragma unroll
      for (int j = 0; j < 4; ++j) {
        int row = wn * 64 + j * 16 + rl;
        bfr[ks][j] = *(const bf16x8*)&Bb[row * 64 + ((c ^ (row & 7)) * 8)];
      }
    }
    if (pf) { stageA(nxt, kt + 2, 0); stageA(nxt, kt + 2, 1); stageA(nxt, kt + 2, 2); }
    __builtin_amdgcn_s_barrier();
    asm volatile("s_waitcnt lgkmcnt(0)" ::: "memory");
    __builtin_amdgcn_sched_barrier(0);
    __builtin_amdgcn_s_setprio(1);
#pragma unroll
    for (int ks = 0; ks < 2; ++ks)
#pragma unroll
      for (int i = 0; i < 2; ++i)
#pragma unroll
        for (int j = 0; j < 4; ++j)
          acc[i][j] = __builtin_amdgcn_mfma_f32_16x16x32_bf16(
              af0[ks][i], bfr[ks][j], acc[i][j], 0, 0, 0);
    __builtin_amdgcn_s_setprio(0);
    __builtin_amdgcn_s_barrier();
    bf16x8 af1[2][2];
#pragma unroll
    for (int ks = 0; ks < 2; ++ks) {
      int c = ks * 4 + kq;
#pragma unroll
      for (int i = 0; i < 2; ++i) {
        int row = wm * 64 + (i + 2) * 16 + rl;
        af1[ks][i] = *(const bf16x8*)&Ab[row * 64 + ((c ^ (row & 7)) * 8)];
      }
    }
    if (pf) { stageA(nxt, kt + 2, 3); stageB(nxt, kt + 2, 0); stageB(nxt, kt + 2, 1); }
    __builtin_amdgcn_s_barrier();
    asm volatile("s_waitcnt lgkmcnt(0)" ::: "memory");
    __builtin_amdgcn_sched_barrier(0);
    __builtin_amdgcn_s_setprio(1);
#pragma unroll
    for (int ks = 0; ks < 2; ++ks)
#pragma unroll
      for (int i = 0; i < 2; ++i)
#pragma unroll
        for (int j = 0; j < 4; ++j)
          acc[i + 2][j] = __builtin_amdgcn_mfma_f32_16x16x32_bf16(
              af1[ks][i], bfr[ks][j], acc[i + 2][j], 0, 0, 0);
    __builtin_amdgcn_s_setprio(0);
    if (kt + 1 < NT) {
      if (pf) asm volatile("s_waitcnt vmcnt(6)" ::: "memory");
      else    asm volatile("s_waitcnt vmcnt(0)" ::: "memory");
      __builtin_amdgcn_s_barrier();
    }
    cur += 1; if (cur >= 3) cur -= 3;
  }

  // Epilogue, write-coalesced (j innermost per row).
  float bv4[4];
#pragma unroll
  for (int j = 0; j < 4; ++j) bv4[j] = bias[n0 + wn * 64 + j * 16 + rl];
#pragma unroll
  for (int i = 0; i < 4; ++i) {
    int rbase = m0 + wm * 64 + i * 16 + (kq << 2);
#pragma unroll
    for (int r = 0; r < 4; ++r) {
      int row = rbase + r;
      float mk = mask[row];
#pragma unroll
      for (int j = 0; j < 4; ++j) {
        int col = n0 + wn * 64 + j * 16 + rl;
        float v = acc[i][j][r] + bv4[j];
        v *= mk;
        if (RELU) v = fmaxf(v, 0.f);
        if (OUT_BF16)
          ((bf16*)Cout)[(size_t)row * N + col] = (bf16)v;
        else
          ((float*)Cout)[(size_t)row * N + col] = v;
      }
    }
  }
}

// ---------------------------------------------------------------------------
// GEMM2: 8-phase 256x256 (frozen). Bijective XCD remap; write-coalesced.
// ---------------------------------------------------------------------------
template <int OUT_BF16, int RELU>
__global__ __launch_bounds__(512, 2) void gemm_ph8_kernel(
    const bf16* __restrict__ A, const bf16* __restrict__ Bt,
    const float* __restrict__ bias, const float* __restrict__ mask,
    void* __restrict__ Cout, int M, int N, int K) {
  __shared__ bf16 As[2][256 * 64];
  __shared__ bf16 Bs[2][256 * 64];
  int ntn = N >> 8;
  int nblk = (M >> 8) * ntn;
  int cpx = nblk >> 3;
  int swz = (blockIdx.x & 7) * cpx + (blockIdx.x >> 3);  // bijective XCD remap
  int mt = swz / ntn, ntb = swz % ntn;
  int m0 = mt << 8, n0 = ntb << 8;
  int t = threadIdx.x, wv = t >> 6, ln = t & 63;
  int wm = wv >> 2, wn = wv & 3;  // 2M x 4N
  int rl = ln & 15, kq = ln >> 4;
  int NT = K >> 6;
  int chunk = t & 7;

  auto stage = [&](int buf, int k1, int arr, int half, int r) {
    int fb = r * 8192 + t * 16;
    int phys = half * 128 + (fb >> 7);
    int q = chunk ^ (phys & 7);
    if (arr == 0) {
      int lg = ((phys >> 6) & 1) * 128 + (phys >> 7) * 64 + (phys & 63);
      async_copy16(A + (size_t)(m0 + lg) * K + k1 + q * 8,
                   (char*)&As[buf][0] + half * 16384 + fb);
    } else {
      int lg = ((phys >> 5) & 3) * 64 + (phys >> 7) * 32 + (phys & 31);
      async_copy16(Bt + (size_t)(n0 + lg) * K + k1 + q * 8,
                   (char*)&Bs[buf][0] + half * 16384 + fb);
    }
  };
  auto ldA = [&](const bf16* Ab, int i, int ks) {
    int pr = (i >> 2) * 128 + wm * 64 + (i & 3) * 16 + rl;
    return *(const bf16x8*)&Ab[pr * 64 + (((ks * 4 + kq) ^ (pr & 7)) * 8)];
  };
  auto ldB = [&](const bf16* Bb, int j, int ks) {
    int pr = (j >> 1) * 128 + wn * 32 + (j & 1) * 16 + rl;
    return *(const bf16x8*)&Bb[pr * 64 + (((ks * 4 + kq) ^ (pr & 7)) * 8)];
  };

  stage(0, 0, 0, 0, 0); stage(0, 0, 0, 0, 1);   // d0.A-lo t0
  stage(0, 0, 1, 0, 0); stage(0, 0, 1, 0, 1);   // d0.B-lo t0
  stage(0, 0, 0, 1, 0); stage(0, 0, 0, 1, 1);   // d0.A-hi t0
  stage(0, 0, 1, 1, 0); stage(0, 0, 1, 1, 1);   // d0.B-hi t0
  stage(1, 64, 0, 0, 0); stage(1, 64, 0, 0, 1); // d1.A-lo t1
  stage(1, 64, 1, 0, 0); stage(1, 64, 1, 0, 1); // d1.B-lo t1
  asm volatile("s_waitcnt vmcnt(4)" ::: "memory");
  __builtin_amdgcn_s_barrier();

  f32x4 acc[8][4] = {};
  bf16x8 aX[4][2], bL[2][2], bH[2][2];
  int NI = NT >> 1;
  for (int it = 0; it < NI; ++it) {
    const bf16* A0 = &As[0][0];
    const bf16* B0 = &Bs[0][0];
    const bf16* A1 = &As[1][0];
    const bf16* B1 = &Bs[1][0];
    int t1k = ((it << 1) + 1) << 6;
    int t2k = ((it << 1) + 2) << 6;
    int t3k = ((it << 1) + 3) << 6;
    bool s2 = ((it << 1) + 2) < NT;
    bool s3 = ((it << 1) + 3) < NT;
    bool last = (it == NI - 1);

    // ---- p1 ----
#pragma unroll
    for (int i = 0; i < 4; ++i) { aX[i][0] = ldA(A0, i, 0); aX[i][1] = ldA(A0, i, 1); }
#pragma unroll
    for (int j = 0; j < 2; ++j) { bL[j][0] = ldB(B0, j, 0); bL[j][1] = ldB(B0, j, 1); }
    stage(1, t1k, 0, 1, 0); stage(1, t1k, 0, 1, 1);
    asm volatile("s_waitcnt lgkmcnt(8)" ::: "memory");
    __builtin_amdgcn_s_barrier();
    asm volatile("s_waitcnt lgkmcnt(0)" ::: "memory");
    __builtin_amdgcn_sched_barrier(0);
    __builtin_amdgcn_s_setprio(1);
#pragma unroll
    for (int ks = 0; ks < 2; ++ks)
#pragma unroll
      for (int i = 0; i < 4; ++i)
#pragma unroll
        for (int j = 0; j < 2; ++j)
          acc[i][j] = __builtin_amdgcn_mfma_f32_16x16x32_bf16(
              aX[i][ks], bL[j][ks], acc[i][j], 0, 0, 0);
    __builtin_amdgcn_s_setprio(0);
    __builtin_amdgcn_s_barrier();
    // ---- p2 ----
#pragma unroll
    for (int j = 0; j < 2; ++j) { bH[j][0] = ldB(B0, j + 2, 0); bH[j][1] = ldB(B0, j + 2, 1); }
    stage(1, t1k, 1, 1, 0); stage(1, t1k, 1, 1, 1);
    __builtin_amdgcn_s_barrier();
    asm volatile("s_waitcnt lgkmcnt(0)" ::: "memory");
    __builtin_amdgcn_sched_barrier(0);
    __builtin_amdgcn_s_setprio(1);
#pragma unroll
    for (int ks = 0; ks < 2; ++ks)
#pragma unroll
      for (int i = 0; i < 4; ++i)
#pragma unroll
        for (int j = 0; j < 2; ++j)
          acc[i][j + 2] = __builtin_amdgcn_mfma_f32_16x16x32_bf16(
              aX[i][ks], bH[j][ks], acc[i][j + 2], 0, 0, 0);
    __builtin_amdgcn_s_setprio(0);
    __builtin_amdgcn_s_barrier();
    // ---- p3 ----
#pragma unroll
    for (int i = 0; i < 4; ++i) { aX[i][0] = ldA(A0, i + 4, 0); aX[i][1] = ldA(A0, i + 4, 1); }
    if (s2) { stage(0, t2k, 0, 0, 0); stage(0, t2k, 0, 0, 1); }
    __builtin_amdgcn_s_barrier();
    asm volatile("s_waitcnt lgkmcnt(0)" ::: "memory");
    __builtin_amdgcn_sched_barrier(0);
    __builtin_amdgcn_s_setprio(1);
#pragma unroll
    for (int ks = 0; ks < 2; ++ks)
#pragma unroll
      for (int i = 0; i < 4; ++i)
#pragma unroll
        for (int j = 0; j < 2; ++j)
          acc[i + 4][j] = __builtin_amdgcn_mfma_f32_16x16x32_bf16(
              aX[i][ks], bL[j][ks], acc[i + 4][j], 0, 0, 0);
    __builtin_amdgcn_s_setprio(0);
    __builtin_amdgcn_s_barrier();
    // ---- p4 ----
    if (s2) { stage(0, t2k, 1, 0, 0); stage(0, t2k, 1, 0, 1); }
    __builtin_amdgcn_s_barrier();
    __builtin_amdgcn_s_setprio(1);
#pragma unroll
    for (int ks = 0; ks < 2; ++ks)
#pragma unroll
      for (int i = 0; i < 4; ++i)
#pragma unroll
        for (int j = 0; j < 2; ++j)
          acc[i + 4][j + 2] = __builtin_amdgcn_mfma_f32_16x16x32_bf16(
              aX[i][ks], bH[j][ks], acc[i + 4][j + 2], 0, 0, 0);
    __builtin_amdgcn_s_setprio(0);
    if (last) asm volatile("s_waitcnt vmcnt(0)" ::: "memory");
    else      asm volatile("s_waitcnt vmcnt(4)" ::: "memory");
    __builtin_amdgcn_s_barrier();
    // ---- p5 ----
#pragma unroll
    for (int i = 0; i < 4; ++i) { aX[i][0] = ldA(A1, i, 0); aX[i][1] = ldA(A1, i, 1); }
#pragma unroll
    for (int j = 0; j < 2; ++j) { bL[j][0] = ldB(B1, j, 0); bL[j][1] = ldB(B1, j, 1); }
    if (s2) { stage(0, t2k, 0, 1, 0); stage(0, t2k, 0, 1, 1); }
    asm volatile("s_waitcnt lgkmcnt(8)" ::: "memory");
    __builtin_amdgcn_s_barrier();
    asm volatile("s_waitcnt lgkmcnt(0)" ::: "memory");
    __builtin_amdgcn_sched_barrier(0);
    __builtin_amdgcn_s_setprio(1);
#pragma unroll
    for (int ks = 0; ks < 2; ++ks)
#pragma unroll
      for (int i = 0; i < 4; ++i)
#pragma unroll
        for (int j = 0; j < 2; ++j)
          acc[i][j] = __builtin_amdgcn_mfma_f32_16x16x32_bf16(
              aX[i][ks], bL[j][ks], acc[i][j], 0, 0, 0);
    __builtin_amdgcn_s_setprio(0);
    __builtin_amdgcn_s_barrier();
    // ---- p6 ----
#pragma unroll
    for (int j = 0; j < 2; ++j) { bH[j][0] = ldB(B1, j + 2, 0); bH[j][1] = ldB(B1, j + 2, 1); }
    if (s2) { stage(0, t2k, 1, 1, 0); stage(0, t2k, 1, 1, 1); }
    __builtin_amdgcn_s_barrier();
    asm volatile("s_waitcnt lgkmcnt(0)" ::: "memory");
    __builtin_amdgcn_sched_barrier(0);
    __builtin_amdgcn_s_setprio(1);
#pragma unroll
    for (int ks = 0; ks < 2; ++ks)
#pragma unroll
      for (int i = 0; i < 4; ++i)
#pragma unroll
        for (int j = 0; j < 2; ++j)
          acc[i][j + 2] = __builtin_amdgcn_mfma_f32_16x16x32_bf16(
              aX[i][ks], bH[j][ks], acc[i][j + 2], 0, 0, 0);
    __builtin_amdgcn_s_setprio(0);
    __builtin_amdgcn_s_barrier();
    // ---- p7 ----
#pragma unroll
    for (int i = 0; i < 4; ++i) { aX[i][0] = ldA(A1, i + 4, 0); aX[i][1] = ldA(A1, i + 4, 1); }
    if (s3) { stage(1, t3k, 0, 0, 0); stage(1, t3k, 0, 0, 1); }
    __builtin_amdgcn_s_barrier();
    asm volatile("s_waitcnt lgkmcnt(0)" ::: "memory");
    __builtin_amdgcn_sched_barrier(0);
    __builtin_amdgcn_s_setprio(1);
#pragma unroll
    for (int ks = 0; ks < 2; ++ks)
#pragma unroll
      for (int i = 0; i < 4; ++i)
#pragma unroll
        for (int j = 0; j < 2; ++j)
          acc[i + 4][j] = __builtin_amdgcn_mfma_f32_16x16x32_bf16(
              aX[i][ks], bL[j][ks], acc[i + 4][j], 0, 0, 0);
    __builtin_amdgcn_s_setprio(0);
    __builtin_amdgcn_s_barrier();
    // ---- p8 ----
    if (s3) { stage(1, t3k, 1, 0, 0); stage(1, t3k, 1, 0, 1); }
    __builtin_amdgcn_s_barrier();
    __builtin_amdgcn_s_setprio(1);
#pragma unroll
    for (int ks = 0; ks < 2; ++ks)
#pragma unroll
      for (int i = 0; i < 4; ++i)
#pragma unroll
        for (int j = 0; j < 2; ++j)
          acc[i + 4][j + 2] = __builtin_amdgcn_mfma_f32_16x16x32_bf16(
              aX[i][ks], bH[j][ks], acc[i + 4][j + 2], 0, 0, 0);
    __builtin_amdgcn_s_setprio(0);
    if (!last) {
      asm volatile("s_waitcnt vmcnt(4)" ::: "memory");
      __builtin_amdgcn_s_barrier();
    }
  }

  // Epilogue, write-coalesced (j innermost per row -> 256B contig per row).
  float bv4[4];
#pragma unroll
  for (int j = 0; j < 4; ++j) bv4[j] = bias[n0 + wn * 64 + j * 16 + rl];
#pragma unroll
  for (int i = 0; i < 8; ++i) {
    int rbase = m0 + wm * 128 + i * 16 + (kq << 2);
#pragma unroll
    for (int r = 0; r < 4; ++r) {
      int row = rbase + r;
      float mk = mask[row];
#pragma unroll
      for (int j = 0; j < 4; ++j) {
        int col = n0 + wn * 64 + j * 16 + rl;
        float v = acc[i][j][r] + bv4[j];
        v *= mk;
        if (RELU) v = fmaxf(v, 0.f);
        if (OUT_BF16)
          ((bf16*)Cout)[(size_t)row * N + col] = (bf16)v;
        else
          ((float*)Cout)[(size_t)row * N + col] = v;
      }
    }
  }
}

// ---------------------------------------------------------------------------
// launcher — 6 kernels (R5 best-measured configuration, restored)
// ---------------------------------------------------------------------------
extern "C" void kernel_launch(void* const* d_in, const int* in_sizes, int n_in,
                              void* d_out, int out_size, void* d_ws, size_t ws_size,
                              hipStream_t stream) {
  const float* ctx = (const float*)d_in[0];
  const float* qst = (const float*)d_in[1];
  const float* mask = (const float*)d_in[2];
  const float* wqv = (const float*)d_in[3];
  const float* wcv = (const float*)d_in[4];
  const float* wmul = (const float*)d_in[5];
  const float* W1 = (const float*)d_in[6];
  const float* b1 = (const float*)d_in[7];
  const float* W2 = (const float*)d_in[8];
  const float* b2 = (const float*)d_in[9];
  float* out = (float*)d_out;
  char* ws = (char*)d_ws;

  bf16* att = (bf16*)(ws);                  // 33554432
  bf16* hbuf = (bf16*)(ws + 33554432);      // 16777216
  bf16* W1T = (bf16*)(ws + 50331648);       // 4194304
  bf16* W2T = (bf16*)(ws + 54525952);       // 4194304
  bf16* qT = (bf16*)(ws + 58720256);        // 1048576
  bf16* qmh = (bf16*)(ws + 59768832);       // 1048576
  bf16* qml = (bf16*)(ws + 60817408);       // 1048576
  float* smax = (float*)(ws + 61865984);    // 32768
  float* q2c = (float*)(ws + 61898752);     // 16384
  float* qw = (float*)(ws + 61915136);      // 4096

  prep_kernel<<<5121, 256, 0, stream>>>(W1, W2, qst, wmul, wqv,
                                        W1T, W2T, qT, qmh, qml, qw, q2c);
  fused_att_kernel<<<512, 256, 0, stream>>>(ctx, qmh, qml, qT, wcv,
                                            qw, smax, att);
  q2c_kernel<<<256, 256, 0, stream>>>(ctx, smax, q2c);
  att3_kernel<<<2048, 256, 0, stream>>>(ctx, q2c, att);
  // GEMM1: h = (att @ W1 + b1) * mask        -> bf16, no relu
  gemm_bt_p2_kernel<1, 0><<<256, 512, 0, stream>>>(
      att, W1T, b1, mask, hbuf, 8192, 1024, 2048);
  // GEMM2: out = relu((h @ W2 + b2) * mask)  -> f32; 8-phase 256^2
  gemm_ph8_kernel<0, 1><<<256, 512, 0, stream>>>(
      hbuf, W2T, b2, mask, out, 8192, 2048, 1024);
}